// Round 10
// baseline (1490.009 us; speedup 1.0000x reference)
//
#include <hip/hip_runtime.h>
#include <hip/hip_bf16.h>
#include <stdint.h>

#define B_ 64
#define S_ 1024
#define E_ 1024
#define H_ 2048
#define NF_ 8
#define NH_ 4
#define NIT_ 10

typedef __attribute__((ext_vector_type(8))) short vshort8;
typedef __attribute__((ext_vector_type(8))) __bf16 vbf16x8;
typedef __attribute__((ext_vector_type(4))) float vfloat4;

// ---------------- async global->LDS, 16B per lane ----------------
typedef const __attribute__((address_space(1))) void* gas1_t;
typedef __attribute__((address_space(3))) void* las3_t;
__device__ __forceinline__ void gload16(const void* g, void* l) {
  __builtin_amdgcn_global_load_lds((gas1_t)g, (las3_t)l, 16, 0, 0);
}

// ---------------- threefry2x32 (JAX-exact) ----------------
__device__ __forceinline__ uint32_t rotl32(uint32_t v, int n) { return (v << n) | (v >> (32 - n)); }

__device__ __forceinline__ void threefry2x32(uint32_t k0, uint32_t k1, uint32_t x0, uint32_t x1,
                                             uint32_t& o0, uint32_t& o1) {
  uint32_t ks2 = k0 ^ k1 ^ 0x1BD11BDAu;
  x0 += k0; x1 += k1;
#define TF_R(r) { x0 += x1; x1 = rotl32(x1, (r)); x1 ^= x0; }
  TF_R(13) TF_R(15) TF_R(26) TF_R(6)
  x0 += k1;  x1 += ks2 + 1u;
  TF_R(17) TF_R(29) TF_R(16) TF_R(24)
  x0 += ks2; x1 += k0 + 2u;
  TF_R(13) TF_R(15) TF_R(26) TF_R(6)
  x0 += k0;  x1 += k1 + 3u;
  TF_R(17) TF_R(29) TF_R(16) TF_R(24)
  x0 += k1;  x1 += ks2 + 4u;
  TF_R(13) TF_R(15) TF_R(26) TF_R(6)
  x0 += ks2; x1 += k0 + 5u;
#undef TF_R
  o0 = x0; o1 = x1;
}

// partitionable threefry 32-bit bits: element i -> bits1 ^ bits2 of threefry(key, (0, i))
__device__ __forceinline__ uint32_t tf_bits_part(uint32_t k0, uint32_t k1, uint32_t i) {
  uint32_t o0, o1;
  threefry2x32(k0, k1, 0u, i, o0, o1);
  return o0 ^ o1;
}

// XLA/Giles erfinv (f32)
__device__ __forceinline__ float erfinv_f(float x) {
  float w = -log1pf(-x * x);
  float p;
  if (w < 5.0f) {
    w -= 2.5f;
    p = 2.81022636e-08f;
    p = 3.43273939e-07f + p * w;
    p = -3.5233877e-06f + p * w;
    p = -4.39150654e-06f + p * w;
    p = 0.00021858087f + p * w;
    p = -0.00125372503f + p * w;
    p = -0.00417768164f + p * w;
    p = 0.246640727f + p * w;
    p = 1.50140941f + p * w;
  } else {
    w = sqrtf(w) - 3.0f;
    p = -0.000200214257f;
    p = 0.000100950558f + p * w;
    p = 0.00134934322f + p * w;
    p = -0.00367342844f + p * w;
    p = 0.00573950773f + p * w;
    p = -0.0076224613f + p * w;
    p = 0.00943887047f + p * w;
    p = 1.00167406f + p * w;
    p = 2.83297682f + p * w;
  }
  return p * x;
}

__device__ __forceinline__ float bits_to_normal(uint32_t bits) {
  uint32_t fb = (bits >> 9) | 0x3F800000u;
  float f = __uint_as_float(fb) - 1.0f;       // [0,1)
  const float lo = -0.99999994f;              // nextafter(-1,0)
  float u = fmaxf(lo, f * 2.0f + lo);
  return 1.41421356f * erfinv_f(u);
}

__device__ __forceinline__ void load_bf8(const __hip_bfloat16* p, float v[8]) {
  vshort8 s = *(const vshort8*)p;
#pragma unroll
  for (int j = 0; j < 8; ++j) {
    uint32_t b = ((uint32_t)(uint16_t)s[j]) << 16;
    v[j] = __uint_as_float(b);
  }
}

// ---------------- ctx = mean over S ----------------
__global__ __launch_bounds__(256) void colmean_partial(const float* __restrict__ cur,
                                                       float* __restrict__ part) {
  int blk = blockIdx.x;            // 512 blocks: b*8 + chunk
  int b = blk >> 3, c = blk & 7;
  int t = threadIdx.x;
  const float* base = cur + ((size_t)b * S_ + (size_t)c * 128) * E_;
  float4 s = {0.f, 0.f, 0.f, 0.f};
  for (int si = 0; si < 128; ++si) {
    float4 v = *(const float4*)(base + (size_t)si * E_ + t * 4);
    s.x += v.x; s.y += v.y; s.z += v.z; s.w += v.w;
  }
  *(float4*)(part + ((size_t)c * B_ + b) * E_ + t * 4) = s;
}

__global__ __launch_bounds__(256) void colmean_final(const float* __restrict__ part,
                                                     float* __restrict__ ctx) {
  int i = blockIdx.x * 256 + threadIdx.x;  // < 65536
  float s = 0.f;
#pragma unroll
  for (int c = 0; c < 8; ++c) s += part[(size_t)c * (B_ * E_) + i];
  ctx[i] = s * (1.0f / S_);
}

// ---------------- f32 -> bf16 elementwise, 8/thread ----------------
__global__ __launch_bounds__(256) void cvt_bf16_v(const float* __restrict__ X,
                                                  __hip_bfloat16* __restrict__ Y) {
  int i = (blockIdx.x * 256 + threadIdx.x) * 8;
  float4 v0 = *(const float4*)(X + i);
  float4 v1 = *(const float4*)(X + i + 4);
  float v[8] = {v0.x, v0.y, v0.z, v0.w, v1.x, v1.y, v1.z, v1.w};
  __hip_bfloat16 o[8];
#pragma unroll
  for (int j = 0; j < 8; ++j) o[j] = __float2bfloat16(v[j]);
  *(vshort8*)&Y[i] = *(vshort8*)o;
}

// ---------------- f32 -> bf16 transpose with scale: Wt[n][k] = s*W[k][n] ----------------
__global__ __launch_bounds__(256) void transpose_to_bf16(const float* __restrict__ W,
                                                         __hip_bfloat16* __restrict__ Wt,
                                                         int K, int N, float scale) {
  __shared__ float tile[32][33];
  int n0 = blockIdx.x * 32, k0 = blockIdx.y * 32;
  int tx = threadIdx.x & 31, ty = threadIdx.x >> 5;
  for (int r = ty; r < 32; r += 8) tile[r][tx] = W[(size_t)(k0 + r) * N + n0 + tx];
  __syncthreads();
  for (int r = ty; r < 32; r += 8)
    Wt[(size_t)(n0 + r) * K + k0 + tx] = __float2bfloat16(tile[tx][r] * scale);
}

// ---------------- skinny bf16 MFMA GEMM (gload16): M=64, tile 64x128, split-K ----------------
__global__ __launch_bounds__(256) void mfma_skinny(const __hip_bfloat16* __restrict__ A,
                                                   const __hip_bfloat16* __restrict__ Bt,
                                                   float* __restrict__ part,
                                                   int N, int K, int lda, int Kc) {
  __shared__ short AS[64 * 32];   // 4 KB linear
  __shared__ short BS[128 * 32];  // 8 KB linear
  int t = threadIdx.x;
  int lane = t & 63, wv = t >> 6;
  int n0 = blockIdx.x * 128;
  int kbeg = blockIdx.y * Kc;
  int wn = wv * 32;
  int lrow = lane & 15, kb = (lane >> 4) * 8;
  vfloat4 acc[4][2];
#pragma unroll
  for (int i = 0; i < 4; ++i)
#pragma unroll
    for (int j = 0; j < 2; ++j) acc[i][j] = (vfloat4){0.f, 0.f, 0.f, 0.f};
  const short* Ag = (const short*)A;
  const short* Bg = (const short*)Bt;
  int arow = lane >> 2;        // 0..15
  int acol = (lane & 3) * 8;   // shorts
  for (int k0 = kbeg; k0 < kbeg + Kc; k0 += 32) {
    gload16(Ag + (size_t)(wv * 16 + arow) * lda + k0 + acol, &AS[(wv * 16) * 32]);
#pragma unroll
    for (int c = 0; c < 2; ++c)
      gload16(Bg + (size_t)(n0 + c * 64 + wv * 16 + arow) * K + k0 + acol,
              &BS[(c * 64 + wv * 16) * 32]);
    __syncthreads();
    vbf16x8 af[4], bq[2];
#pragma unroll
    for (int i = 0; i < 4; ++i) af[i] = *(const vbf16x8*)&AS[(i * 16 + lrow) * 32 + kb];
#pragma unroll
    for (int j = 0; j < 2; ++j) bq[j] = *(const vbf16x8*)&BS[(wn + j * 16 + lrow) * 32 + kb];
#pragma unroll
    for (int i = 0; i < 4; ++i)
#pragma unroll
      for (int j = 0; j < 2; ++j)
        acc[i][j] = __builtin_amdgcn_mfma_f32_16x16x32_bf16(af[i], bq[j], acc[i][j], 0, 0, 0);
    __syncthreads();
  }
  size_t zbase = (size_t)blockIdx.y * 64;
  int crow0 = (lane >> 4) * 4;
  int ccol0 = n0 + wn + lrow;
#pragma unroll
  for (int i = 0; i < 4; ++i) {
#pragma unroll
    for (int j = 0; j < 2; ++j) {
      int col = ccol0 + j * 16;
#pragma unroll
      for (int r = 0; r < 4; ++r) {
        int rowi = i * 16 + crow0 + r;
        part[(zbase + rowi) * N + col] = acc[i][j][r];
      }
    }
  }
}

// ---------------- C[64][N] = sum_z part[z][64][N] + bias (opt. bf16 copy) ----------------
template <bool BF16OUT>
__global__ __launch_bounds__(256) void reduce_bias(const float* __restrict__ part,
                                                   const float* __restrict__ bias,
                                                   float* __restrict__ C,
                                                   __hip_bfloat16* __restrict__ Cb,
                                                   int N, int SK) {
  int i = blockIdx.x * 256 + threadIdx.x;  // < 64*N
  int col = i & (N - 1);                   // N is a power of two
  float s = bias[col];
  for (int z = 0; z < SK; ++z) s += part[(size_t)z * 64 * N + i];
  C[i] = s;
  if (BF16OUT) Cb[i] = __float2bfloat16(s);
}

// ---------------- combined cterm reduce: out[64][4096], bias = [rn_b1 | en_b1] ----------------
__global__ __launch_bounds__(256) void reduce_cterm(const float* __restrict__ part,
                                                    const float* __restrict__ rn_b1,
                                                    const float* __restrict__ en_b1,
                                                    float* __restrict__ out, int SK) {
  int i = blockIdx.x * 256 + threadIdx.x;  // < 64*4096
  int col = i & 4095;
  float s = (col < 2048) ? rn_b1[col] : en_b1[col - 2048];
  for (int z = 0; z < SK; ++z) s += part[(size_t)z * 64 * 4096 + i];
  out[i] = s;
}

// ---------------- fused split-K reduce + LayerNorm(2048) + relu -> bf16 (64 rows) ----------------
__global__ __launch_bounds__(256) void ln2048red(const float* __restrict__ part,
                                                 const float* __restrict__ bias,
                                                 const float* __restrict__ g,
                                                 const float* __restrict__ be,
                                                 __hip_bfloat16* __restrict__ out, int SK) {
  __shared__ float red[256];
  int row = blockIdx.x, t = threadIdx.x;
  int j0 = t * 8;
  float v[8];
  *(float4*)&v[0] = *(const float4*)(bias + j0);
  *(float4*)&v[4] = *(const float4*)(bias + j0 + 4);
  for (int z = 0; z < SK; ++z) {
    const float* p = part + (size_t)z * 64 * 2048 + (size_t)row * 2048 + j0;
    float4 a0 = *(const float4*)p, a1 = *(const float4*)(p + 4);
    v[0] += a0.x; v[1] += a0.y; v[2] += a0.z; v[3] += a0.w;
    v[4] += a1.x; v[5] += a1.y; v[6] += a1.z; v[7] += a1.w;
  }
  float s = 0.f;
#pragma unroll
  for (int j = 0; j < 8; ++j) s += v[j];
  red[t] = s; __syncthreads();
  for (int k = 128; k > 0; k >>= 1) { if (t < k) red[t] += red[t + k]; __syncthreads(); }
  float mean = red[0] * (1.0f / 2048.0f);
  __syncthreads();
  float s2 = 0.f;
#pragma unroll
  for (int j = 0; j < 8; ++j) { float d = v[j] - mean; s2 += d * d; }
  red[t] = s2; __syncthreads();
  for (int k = 128; k > 0; k >>= 1) { if (t < k) red[t] += red[t + k]; __syncthreads(); }
  float rstd = rsqrtf(red[0] * (1.0f / 2048.0f) + 1e-5f);
  __hip_bfloat16 o[8];
#pragma unroll
  for (int j = 0; j < 8; ++j) {
    float y = (v[j] - mean) * rstd * g[j0 + j] + be[j0 + j];
    o[j] = __float2bfloat16(fmaxf(y, 0.f));
  }
  *(vshort8*)&out[(size_t)row * 2048 + j0] = *(vshort8*)o;
}

// ---------------- combine (bf16 G) + LayerNorm + relu -> bf16 ----------------
// NEIGH=1: v = G[row][j] + G[prow][2048+j] + G[nrow][2048+j] + cterm[b][j] (G stride 4096)
// NEIGH=0: v = G[row][j] + cterm[b][j]                                    (G stride 2048)
template <int NEIGH>
__global__ __launch_bounds__(256) void ln_comb(const __hip_bfloat16* __restrict__ G,
                                               const float* __restrict__ cterm, int cstride,
                                               const float* __restrict__ g,
                                               const float* __restrict__ be,
                                               __hip_bfloat16* __restrict__ out) {
  __shared__ float red[256];
  int row = blockIdx.x, t = threadIdx.x;
  int j0 = t * 8;
  const int GS = NEIGH ? 4096 : 2048;
  float v[8];
  load_bf8(G + (size_t)row * GS + j0, v);
  {
    const float* p = cterm + (size_t)(row >> 5) * cstride + j0;
    float4 a0 = *(const float4*)p, a1 = *(const float4*)(p + 4);
    v[0] += a0.x; v[1] += a0.y; v[2] += a0.z; v[3] += a0.w;
    v[4] += a1.x; v[5] += a1.y; v[6] += a1.z; v[7] += a1.w;
  }
  if (NEIGH) {
    int f = row & 7;
    int prow = (f == 0) ? row : row - 1;
    int nrow = (f == NF_ - 1) ? row : row + 1;
    float a[8], b[8];
    load_bf8(G + (size_t)prow * 4096 + 2048 + j0, a);
    load_bf8(G + (size_t)nrow * 4096 + 2048 + j0, b);
#pragma unroll
    for (int j = 0; j < 8; ++j) v[j] += a[j] + b[j];
  }
  float s = 0.f;
#pragma unroll
  for (int j = 0; j < 8; ++j) s += v[j];
  red[t] = s; __syncthreads();
  for (int k = 128; k > 0; k >>= 1) { if (t < k) red[t] += red[t + k]; __syncthreads(); }
  float mean = red[0] * (1.0f / 2048.0f);
  __syncthreads();
  float s2 = 0.f;
#pragma unroll
  for (int j = 0; j < 8; ++j) { float d = v[j] - mean; s2 += d * d; }
  red[t] = s2; __syncthreads();
  for (int k = 128; k > 0; k >>= 1) { if (t < k) red[t] += red[t + k]; __syncthreads(); }
  float rstd = rsqrtf(red[0] * (1.0f / 2048.0f) + 1e-5f);
  __hip_bfloat16 o[8];
#pragma unroll
  for (int j = 0; j < 8; ++j) {
    float y = (v[j] - mean) * rstd * g[j0 + j] + be[j0 + j];
    o[j] = __float2bfloat16(fmaxf(y, 0.f));
  }
  *(vshort8*)&out[(size_t)row * 2048 + j0] = *(vshort8*)o;
}

// ---------------- m97-structure bf16 GEMM: 128x128 tile, BK=32, bf16 raw output ----------------
__global__ __launch_bounds__(256) void gemm_bf(const __hip_bfloat16* __restrict__ A,
                                               const __hip_bfloat16* __restrict__ Bt,
                                               __hip_bfloat16* __restrict__ Cb,
                                               int M, int N, int K) {
  __shared__ short Als[128 * 32];  // 8 KB linear
  __shared__ short Bls[128 * 32];  // 8 KB linear
  int t = threadIdx.x;
  int lane = t & 63, wv = t >> 6;
  int n0 = blockIdx.x * 128, m0 = blockIdx.y * 128;
  int wm = (wv >> 1) * 64, wn = (wv & 1) * 64;
  int lrow = lane & 15, kb = (lane >> 4) * 8;
  vfloat4 acc[4][4];
#pragma unroll
  for (int i = 0; i < 4; ++i)
#pragma unroll
    for (int j = 0; j < 4; ++j) acc[i][j] = (vfloat4){0.f, 0.f, 0.f, 0.f};
  const short* Ag = (const short*)A;
  const short* Bg = (const short*)Bt;
  int arow = lane >> 2;        // 0..15 (4 lanes per 64B row)
  int acol = (lane & 3) * 8;   // shorts
  for (int k0 = 0; k0 < K; k0 += 32) {
#pragma unroll
    for (int c = 0; c < 2; ++c) {
      gload16(Ag + (size_t)(m0 + c * 64 + wv * 16 + arow) * K + k0 + acol,
              &Als[(c * 64 + wv * 16) * 32]);
      gload16(Bg + (size_t)(n0 + c * 64 + wv * 16 + arow) * K + k0 + acol,
              &Bls[(c * 64 + wv * 16) * 32]);
    }
    __syncthreads();
    vbf16x8 af[4], bq[4];
#pragma unroll
    for (int i = 0; i < 4; ++i) af[i] = *(const vbf16x8*)&Als[(wm + i * 16 + lrow) * 32 + kb];
#pragma unroll
    for (int j = 0; j < 4; ++j) bq[j] = *(const vbf16x8*)&Bls[(wn + j * 16 + lrow) * 32 + kb];
#pragma unroll
    for (int i = 0; i < 4; ++i)
#pragma unroll
      for (int j = 0; j < 4; ++j)
        acc[i][j] = __builtin_amdgcn_mfma_f32_16x16x32_bf16(af[i], bq[j], acc[i][j], 0, 0, 0);
    __syncthreads();
  }
  int crow0 = m0 + wm + (lane >> 4) * 4;
  int ccol0 = n0 + wn + lrow;
#pragma unroll
  for (int i = 0; i < 4; ++i) {
#pragma unroll
    for (int j = 0; j < 4; ++j) {
      int col = ccol0 + j * 16;
#pragma unroll
      for (int r = 0; r < 4; ++r)
        Cb[(size_t)(crow0 + i * 16 + r) * N + col] = __float2bfloat16(acc[i][j][r]);
    }
  }
}

// ---------------- bf16 MFMA GEMM via global_load_lds, BK=64 ----------------
// tile: 128(M) x 64(N), 4 waves (2x2), acc[4][2].
// MODE 1: bias+relu (f32 out); MODE 2: fused x-update + bf16 x copy
template <int MODE>
__global__ __launch_bounds__(256) void gemm_gl(const __hip_bfloat16* __restrict__ A,
                                               const __hip_bfloat16* __restrict__ Bt,
                                               const float* __restrict__ bias,
                                               float* __restrict__ Cout,
                                               __hip_bfloat16* __restrict__ Cbout,
                                               int M, int N, int K, int it) {
  __shared__ short Als[128 * 64];  // 16 KB linear
  __shared__ short Bls[64 * 64];   // 8 KB linear
  int t = threadIdx.x;
  int lane = t & 63, wv = t >> 6;
  int n0 = blockIdx.x * 64, m0 = blockIdx.y * 128;
  int wm = (wv >> 1) * 64, wn = (wv & 1) * 32;
  int lrow = lane & 15, kb = (lane >> 4) * 8;
  vfloat4 acc[4][2];
#pragma unroll
  for (int i = 0; i < 4; ++i)
#pragma unroll
    for (int j = 0; j < 2; ++j) acc[i][j] = (vfloat4){0.f, 0.f, 0.f, 0.f};
  const short* Ag = (const short*)A;
  const short* Bg = (const short*)Bt;
  int arow = lane >> 3;        // 0..7 (8 lanes per 128B row)
  int acol = (lane & 7) * 8;   // shorts
  for (int k0 = 0; k0 < K; k0 += 64) {
#pragma unroll
    for (int c = 0; c < 4; ++c)
      gload16(Ag + (size_t)(m0 + c * 32 + wv * 8 + arow) * K + k0 + acol,
              &Als[(c * 32 + wv * 8) * 64]);
#pragma unroll
    for (int c = 0; c < 2; ++c)
      gload16(Bg + (size_t)(n0 + c * 32 + wv * 8 + arow) * K + k0 + acol,
              &Bls[(c * 32 + wv * 8) * 64]);
    __syncthreads();
    vbf16x8 af[2][4], bq[2][2];
#pragma unroll
    for (int ks = 0; ks < 2; ++ks) {
#pragma unroll
      for (int i = 0; i < 4; ++i)
        af[ks][i] = *(const vbf16x8*)&Als[(wm + i * 16 + lrow) * 64 + ks * 32 + kb];
#pragma unroll
      for (int j = 0; j < 2; ++j)
        bq[ks][j] = *(const vbf16x8*)&Bls[(wn + j * 16 + lrow) * 64 + ks * 32 + kb];
    }
#pragma unroll
    for (int ks = 0; ks < 2; ++ks)
#pragma unroll
      for (int i = 0; i < 4; ++i)
#pragma unroll
        for (int j = 0; j < 2; ++j)
          acc[i][j] = __builtin_amdgcn_mfma_f32_16x16x32_bf16(af[ks][i], bq[ks][j], acc[i][j], 0, 0, 0);
    __syncthreads();
  }
  int crow0 = m0 + wm + (lane >> 4) * 4;
  int ccol0 = n0 + wn + lrow;
  if (MODE == 2) {
    uint32_t key0 = 0, key1 = 0;
    bool addn = (it < NIT_ - 1);
    if (addn) threefry2x32(0u, 7u, 0u, (uint32_t)it, key0, key1);  // fold_in(key(7), it)
#pragma unroll
    for (int i = 0; i < 4; ++i) {
#pragma unroll
      for (int j = 0; j < 2; ++j) {
        int col = ccol0 + j * 16;
        float bv = bias[col];
#pragma unroll
        for (int r = 0; r < 4; ++r) {
          uint32_t idx = (uint32_t)(crow0 + i * 16 + r) * N + col;
          float xv = Cout[idx] - 0.1f * (acc[i][j][r] + bv);
          if (addn) xv += 0.01f * bits_to_normal(tf_bits_part(key0, key1, idx));
          Cout[idx] = xv;
          Cbout[idx] = __float2bfloat16(xv);
        }
      }
    }
  } else {
#pragma unroll
    for (int i = 0; i < 4; ++i) {
#pragma unroll
      for (int j = 0; j < 2; ++j) {
        int col = ccol0 + j * 16;
        float bv = bias[col];
#pragma unroll
        for (int r = 0; r < 4; ++r) {
          float v = acc[i][j][r] + bv;
          if (MODE == 1) v = fmaxf(v, 0.f);
          Cout[(size_t)(crow0 + i * 16 + r) * N + col] = v;
        }
      }
    }
  }
}

// ---------------- fused: traj = reduce(part)+bias; x[b,h] = traj + 0.1*normal ----------------
__global__ __launch_bounds__(256) void reduce_traj_noise(const float* __restrict__ part,
                                                         const float* __restrict__ bias,
                                                         float* __restrict__ x,
                                                         __hip_bfloat16* __restrict__ xb,
                                                         int SK) {
  int i = blockIdx.x * 256 + threadIdx.x;  // < 524288 (traj index)
  int fe = i & 8191;
  float s = bias[fe];
  for (int z = 0; z < SK; ++z) s += part[(size_t)z * 524288 + i];
  int b = i >> 13;
#pragma unroll
  for (int h = 0; h < NH_; ++h) {
    uint32_t xi = (uint32_t)(b * 32768 + h * 8192 + fe);
    float xv = s + 0.1f * bits_to_normal(tf_bits_part(0u, 42u, xi));
    x[xi] = xv;
    xb[xi] = __float2bfloat16(xv);
  }
}

// ---------------- per-row dot with en_w3 ----------------
__global__ __launch_bounds__(256) void rowdot(const float* __restrict__ X2,
                                              const float* __restrict__ w3,
                                              const float* __restrict__ b3,
                                              float* __restrict__ srow) {
  __shared__ float red[256];
  int row = blockIdx.x, t = threadIdx.x;
  const float* xr = X2 + (size_t)row * E_;
  float s = 0.f;
  for (int c = t; c < E_; c += 256) s += xr[c] * w3[c];
  red[t] = s; __syncthreads();
  for (int k = 128; k > 0; k >>= 1) { if (t < k) red[t] += red[t + k]; __syncthreads(); }
  if (t == 0) srow[row] = red[0] + b3[0];
}

// ---------------- energies[bh] = coherence + 0.1*smoothness + supervision ----------------
__global__ __launch_bounds__(256) void energy_final(const float* __restrict__ x,
                                                    const float* __restrict__ ft,
                                                    const float* __restrict__ srow,
                                                    float* __restrict__ energ) {
  __shared__ float red[256];
  int bh = blockIdx.x, t = threadIdx.x;
  int b = bh >> 2;
  const float* xb = x + (size_t)bh * (NF_ * E_);
  const float* fb = ft + (size_t)b * (NF_ * E_);
  float sup = 0.f;
  for (int i = t; i < NF_ * E_; i += 256) { float d = xb[i] - fb[i]; sup += d * d; }
  red[t] = sup; __syncthreads();
  for (int k = 128; k > 0; k >>= 1) { if (t < k) red[t] += red[t + k]; __syncthreads(); }
  float supervision = red[0] / (NF_ * E_);
  float smooth = 0.f;
  for (int d = 0; d < NF_ - 1; ++d) {
    __syncthreads();
    float sd = 0.f;
    for (int e = t; e < E_; e += 256) {
      float df = xb[(d + 1) * E_ + e] - xb[d * E_ + e];
      sd += df * df;
    }
    red[t] = sd; __syncthreads();
    for (int k = 128; k > 0; k >>= 1) { if (t < k) red[t] += red[t + k]; __syncthreads(); }
    smooth += sqrtf(red[0]);
  }
  smooth *= (1.0f / (NF_ - 1));
  if (t == 0) {
    float coh = 0.f;
    for (int f = 0; f < NF_; ++f) coh += srow[bh * NF_ + f];
    coh *= (1.0f / NF_);
    energ[bh] = coh + 0.1f * smooth + supervision;
  }
}

__global__ void softmax_probs(const float* __restrict__ energ, float* __restrict__ probs) {
  int b = threadIdx.x;
  if (b < B_) {
    float e[NH_], m = -1e30f;
#pragma unroll
    for (int h = 0; h < NH_; ++h) { e[h] = -energ[b * NH_ + h]; m = fmaxf(m, e[h]); }
    float s = 0.f, p[NH_];
#pragma unroll
    for (int h = 0; h < NH_; ++h) { p[h] = expf(e[h] - m); s += p[h]; }
#pragma unroll
    for (int h = 0; h < NH_; ++h) probs[b * NH_ + h] = p[h] / s;
  }
}

__global__ __launch_bounds__(256) void predict(const float* __restrict__ x,
                                               const float* __restrict__ probs,
                                               float* __restrict__ out) {
  int i = blockIdx.x * 256 + threadIdx.x;  // < 524288
  int b = i >> 13, fe = i & 8191;
  float s = 0.f;
#pragma unroll
  for (int h = 0; h < NH_; ++h) s += x[(size_t)(b * NH_ + h) * 8192 + fe] * probs[b * NH_ + h];
  out[i] = s;
}

extern "C" void kernel_launch(void* const* d_in, const int* in_sizes, int n_in,
                              void* d_out, int out_size, void* d_ws, size_t ws_size,
                              hipStream_t stream) {
  const float* cur   = (const float*)d_in[0];
  const float* ftrue = (const float*)d_in[1];
  const float* ce_w1 = (const float*)d_in[2];
  const float* ce_b1 = (const float*)d_in[3];
  const float* ce_g  = (const float*)d_in[4];
  const float* ce_be = (const float*)d_in[5];
  const float* ce_w2 = (const float*)d_in[6];
  const float* ce_b2 = (const float*)d_in[7];
  const float* tp_w1 = (const float*)d_in[8];
  const float* tp_b1 = (const float*)d_in[9];
  const float* tp_g  = (const float*)d_in[10];
  const float* tp_be = (const float*)d_in[11];
  const float* tp_w2 = (const float*)d_in[12];
  const float* tp_b2 = (const float*)d_in[13];
  const float* en_w1 = (const float*)d_in[14];
  const float* en_b1 = (const float*)d_in[15];
  const float* en_g  = (const float*)d_in[16];
  const float* en_be = (const float*)d_in[17];
  const float* en_w2 = (const float*)d_in[18];
  const float* en_b2 = (const float*)d_in[19];
  const float* en_w3 = (const float*)d_in[20];
  const float* en_b3 = (const float*)d_in[21];
  const float* rn_w1 = (const float*)d_in[22];
  const float* rn_b1 = (const float*)d_in[23];
  const float* rn_g  = (const float*)d_in[24];
  const float* rn_be = (const float*)d_in[25];
  const float* rn_w2 = (const float*)d_in[26];
  const float* rn_b2 = (const float*)d_in[27];
  (void)in_sizes; (void)n_in; (void)out_size; (void)ws_size;

  char* w = (char*)d_ws;
  size_t off = 0;
  auto alloc = [&](size_t bytes) -> void* {
    void* p = w + off;
    off += (bytes + 255) & ~(size_t)255;
    return p;
  };
  float* part   = (float*)alloc((size_t)8 * B_ * E_ * 4);
  float* ctx    = (float*)alloc((size_t)B_ * E_ * 4);
  float* g1     = (float*)alloc((size_t)B_ * H_ * 4);
  float* x      = (float*)alloc((size_t)2097152 * 4);
  float* skpart = (float*)alloc((size_t)8 * 64 * 8192 * 4);  // 16.78 MB split-K partials
  __hip_bfloat16* Gb = (__hip_bfloat16*)alloc((size_t)2048 * 4096 * 2);  // big-GEMM output (bf16)
  float* u      = (float*)alloc((size_t)2048 * 1024 * 4);
  __hip_bfloat16* ub   = (__hip_bfloat16*)alloc((size_t)2048 * 2048 * 2);
  __hip_bfloat16* x_b  = (__hip_bfloat16*)alloc((size_t)2048 * 1024 * 2);
  float* srow   = (float*)alloc((size_t)2048 * 4);
  float* energ  = (float*)alloc((size_t)256 * 4);
  float* probs  = (float*)alloc((size_t)256 * 4);
  float* ctermcat = (float*)alloc((size_t)B_ * 4096 * 4);  // [cterm | ecterm]
  __hip_bfloat16* Wcat_t  = (__hip_bfloat16*)alloc((size_t)4096 * 1024 * 2);  // [W1a; 0.5*W1c]^T
  __hip_bfloat16* Wbcat_t = (__hip_bfloat16*)alloc((size_t)4096 * 1024 * 2);  // [W1b; en_w1b]^T
  __hip_bfloat16* rn_w2t = (__hip_bfloat16*)alloc((size_t)1024 * 2048 * 2);
  __hip_bfloat16* en1a_t = (__hip_bfloat16*)alloc((size_t)2048 * 1024 * 2);
  __hip_bfloat16* en_w2t = (__hip_bfloat16*)alloc((size_t)1024 * 2048 * 2);
  __hip_bfloat16* ctx_b  = (__hip_bfloat16*)alloc((size_t)B_ * E_ * 2);
  __hip_bfloat16* ctxh_b = (__hip_bfloat16*)alloc((size_t)B_ * H_ * 2);
  __hip_bfloat16* lnb    = (__hip_bfloat16*)alloc((size_t)B_ * H_ * 2);
  __hip_bfloat16* cw1t = (__hip_bfloat16*)alloc((size_t)2048 * 1024 * 2);
  __hip_bfloat16* cw2t = (__hip_bfloat16*)alloc((size_t)2048 * 2048 * 2);
  __hip_bfloat16* tw1t = (__hip_bfloat16*)alloc((size_t)2048 * 2048 * 2);
  __hip_bfloat16* tw2t = (__hip_bfloat16*)alloc((size_t)8192 * 2048 * 2);

  // ctx = mean_S
  colmean_partial<<<512, 256, 0, stream>>>(cur, part);
  colmean_final<<<256, 256, 0, stream>>>(part, ctx);

  // weight prep (bf16, chunked for the concat-elimination)
  transpose_to_bf16<<<dim3(64, 32), 256, 0, stream>>>(rn_w1, Wcat_t, 1024, 2048, 1.0f);
  transpose_to_bf16<<<dim3(64, 32), 256, 0, stream>>>(rn_w1 + (size_t)2048 * 2048,
                                                      Wcat_t + (size_t)2048 * 1024, 1024, 2048, 0.5f);
  transpose_to_bf16<<<dim3(64, 32), 256, 0, stream>>>(rn_w1 + (size_t)1024 * 2048, Wbcat_t, 1024, 2048, 1.0f);
  transpose_to_bf16<<<dim3(64, 32), 256, 0, stream>>>(en_w1 + (size_t)1024 * 2048,
                                                      Wbcat_t + (size_t)2048 * 1024, 1024, 2048, 1.0f);
  transpose_to_bf16<<<dim3(32, 64), 256, 0, stream>>>(rn_w2, rn_w2t, 2048, 1024, 1.0f);
  transpose_to_bf16<<<dim3(64, 32), 256, 0, stream>>>(en_w1, en1a_t, 1024, 2048, 1.0f);
  transpose_to_bf16<<<dim3(32, 64), 256, 0, stream>>>(en_w2, en_w2t, 2048, 1024, 1.0f);
  transpose_to_bf16<<<dim3(64, 32), 256, 0, stream>>>(ce_w1, cw1t, 1024, 2048, 1.0f);
  transpose_to_bf16<<<dim3(64, 64), 256, 0, stream>>>(ce_w2, cw2t, 2048, 2048, 1.0f);
  transpose_to_bf16<<<dim3(64, 64), 256, 0, stream>>>(tp_w1, tw1t, 2048, 2048, 1.0f);
  transpose_to_bf16<<<dim3(256, 64), 256, 0, stream>>>(tp_w2, tw2t, 2048, 8192, 1.0f);

  // ---- context/trajectory path (plain bf16 skinny GEMMs, M=64) ----
  cvt_bf16_v<<<32, 256, 0, stream>>>(ctx, ctx_b);
  mfma_skinny<<<dim3(16, 4), 256, 0, stream>>>(ctx_b, cw1t, skpart, 2048, 1024, 1024, 256);
  ln2048red<<<B_, 256, 0, stream>>>(skpart, ce_b1, ce_g, ce_be, lnb, 4);
  mfma_skinny<<<dim3(16, 8), 256, 0, stream>>>(lnb, cw2t, skpart, 2048, 2048, 2048, 256);
  reduce_bias<true><<<512, 256, 0, stream>>>(skpart, ce_b2, g1, ctxh_b, 2048, 8);
  mfma_skinny<<<dim3(16, 8), 256, 0, stream>>>(ctxh_b, tw1t, skpart, 2048, 2048, 2048, 256);
  ln2048red<<<B_, 256, 0, stream>>>(skpart, tp_b1, tp_g, tp_be, lnb, 8);
  mfma_skinny<<<dim3(64, 8), 256, 0, stream>>>(lnb, tw2t, skpart, 8192, 2048, 2048, 256);
  reduce_traj_noise<<<2048, 256, 0, stream>>>(skpart, tp_b2, x, x_b, 8);

  // constant terms (once): [cterm | ecterm] = ce @ [W1b | en_w1b] + [rn_b1 | en_b1]
  mfma_skinny<<<dim3(32, 4), 256, 0, stream>>>(ctxh_b, Wbcat_t, skpart, 4096, 1024, 2048, 256);
  reduce_cterm<<<1024, 256, 0, stream>>>(skpart, rn_b1, en_b1, ctermcat, 4);

  // refinement loop: 3 dispatches/iter
  for (int it = 0; it < NIT_; ++it) {
    gemm_bf<<<dim3(32, 16), 256, 0, stream>>>(x_b, Wcat_t, Gb, 2048, 4096, 1024);
    ln_comb<1><<<2048, 256, 0, stream>>>(Gb, ctermcat, 4096, rn_g, rn_be, ub);
    gemm_gl<2><<<dim3(16, 16), 256, 0, stream>>>(ub, rn_w2t, rn_b2, x, x_b,
                                                 2048, 1024, 2048, it);
  }

  // energy + softmax + weighted prediction
  gemm_bf<<<dim3(16, 16), 256, 0, stream>>>(x_b, en1a_t, Gb, 2048, 2048, 1024);
  ln_comb<0><<<2048, 256, 0, stream>>>(Gb, ctermcat + 2048, 4096, en_g, en_be, ub);
  gemm_gl<1><<<dim3(16, 16), 256, 0, stream>>>(ub, en_w2t, en_b2, u, nullptr,
                                               2048, 1024, 2048, 0);
  rowdot<<<2048, 256, 0, stream>>>(u, en_w3, en_b3, srow);
  energy_final<<<256, 256, 0, stream>>>(x, ftrue, srow, energ);
  softmax_probs<<<1, 64, 0, stream>>>(energ, probs);
  predict<<<2048, 256, 0, stream>>>(x, probs, (float*)d_out);
}

// Round 11
// 1316.071 us; speedup vs baseline: 1.1322x; 1.1322x over previous
//
#include <hip/hip_runtime.h>
#include <hip/hip_bf16.h>
#include <stdint.h>

#define B_ 64
#define S_ 1024
#define E_ 1024
#define H_ 2048
#define NF_ 8
#define NH_ 4
#define NIT_ 10

typedef __attribute__((ext_vector_type(8))) short vshort8;
typedef __attribute__((ext_vector_type(8))) __bf16 vbf16x8;
typedef __attribute__((ext_vector_type(4))) float vfloat4;

// ---------------- async global->LDS, 16B per lane ----------------
typedef const __attribute__((address_space(1))) void* gas1_t;
typedef __attribute__((address_space(3))) void* las3_t;
__device__ __forceinline__ void gload16(const void* g, void* l) {
  __builtin_amdgcn_global_load_lds((gas1_t)g, (las3_t)l, 16, 0, 0);
}

// ---------------- threefry2x32 (JAX-exact) ----------------
__device__ __forceinline__ uint32_t rotl32(uint32_t v, int n) { return (v << n) | (v >> (32 - n)); }

__device__ __forceinline__ void threefry2x32(uint32_t k0, uint32_t k1, uint32_t x0, uint32_t x1,
                                             uint32_t& o0, uint32_t& o1) {
  uint32_t ks2 = k0 ^ k1 ^ 0x1BD11BDAu;
  x0 += k0; x1 += k1;
#define TF_R(r) { x0 += x1; x1 = rotl32(x1, (r)); x1 ^= x0; }
  TF_R(13) TF_R(15) TF_R(26) TF_R(6)
  x0 += k1;  x1 += ks2 + 1u;
  TF_R(17) TF_R(29) TF_R(16) TF_R(24)
  x0 += ks2; x1 += k0 + 2u;
  TF_R(13) TF_R(15) TF_R(26) TF_R(6)
  x0 += k0;  x1 += k1 + 3u;
  TF_R(17) TF_R(29) TF_R(16) TF_R(24)
  x0 += k1;  x1 += ks2 + 4u;
  TF_R(13) TF_R(15) TF_R(26) TF_R(6)
  x0 += ks2; x1 += k0 + 5u;
#undef TF_R
  o0 = x0; o1 = x1;
}

// partitionable threefry 32-bit bits: element i -> bits1 ^ bits2 of threefry(key, (0, i))
__device__ __forceinline__ uint32_t tf_bits_part(uint32_t k0, uint32_t k1, uint32_t i) {
  uint32_t o0, o1;
  threefry2x32(k0, k1, 0u, i, o0, o1);
  return o0 ^ o1;
}

// XLA/Giles erfinv (f32)
__device__ __forceinline__ float erfinv_f(float x) {
  float w = -log1pf(-x * x);
  float p;
  if (w < 5.0f) {
    w -= 2.5f;
    p = 2.81022636e-08f;
    p = 3.43273939e-07f + p * w;
    p = -3.5233877e-06f + p * w;
    p = -4.39150654e-06f + p * w;
    p = 0.00021858087f + p * w;
    p = -0.00125372503f + p * w;
    p = -0.00417768164f + p * w;
    p = 0.246640727f + p * w;
    p = 1.50140941f + p * w;
  } else {
    w = sqrtf(w) - 3.0f;
    p = -0.000200214257f;
    p = 0.000100950558f + p * w;
    p = 0.00134934322f + p * w;
    p = -0.00367342844f + p * w;
    p = 0.00573950773f + p * w;
    p = -0.0076224613f + p * w;
    p = 0.00943887047f + p * w;
    p = 1.00167406f + p * w;
    p = 2.83297682f + p * w;
  }
  return p * x;
}

__device__ __forceinline__ float bits_to_normal(uint32_t bits) {
  uint32_t fb = (bits >> 9) | 0x3F800000u;
  float f = __uint_as_float(fb) - 1.0f;       // [0,1)
  const float lo = -0.99999994f;              // nextafter(-1,0)
  float u = fmaxf(lo, f * 2.0f + lo);
  return 1.41421356f * erfinv_f(u);
}

__device__ __forceinline__ void load_bf8(const __hip_bfloat16* p, float v[8]) {
  vshort8 s = *(const vshort8*)p;
#pragma unroll
  for (int j = 0; j < 8; ++j) {
    uint32_t b = ((uint32_t)(uint16_t)s[j]) << 16;
    v[j] = __uint_as_float(b);
  }
}

// ---------------- ctx = mean over S ----------------
__global__ __launch_bounds__(256) void colmean_partial(const float* __restrict__ cur,
                                                       float* __restrict__ part) {
  int blk = blockIdx.x;            // 512 blocks: b*8 + chunk
  int b = blk >> 3, c = blk & 7;
  int t = threadIdx.x;
  const float* base = cur + ((size_t)b * S_ + (size_t)c * 128) * E_;
  float4 s = {0.f, 0.f, 0.f, 0.f};
  for (int si = 0; si < 128; ++si) {
    float4 v = *(const float4*)(base + (size_t)si * E_ + t * 4);
    s.x += v.x; s.y += v.y; s.z += v.z; s.w += v.w;
  }
  *(float4*)(part + ((size_t)c * B_ + b) * E_ + t * 4) = s;
}

__global__ __launch_bounds__(256) void colmean_final(const float* __restrict__ part,
                                                     float* __restrict__ ctx) {
  int i = blockIdx.x * 256 + threadIdx.x;  // < 65536
  float s = 0.f;
#pragma unroll
  for (int c = 0; c < 8; ++c) s += part[(size_t)c * (B_ * E_) + i];
  ctx[i] = s * (1.0f / S_);
}

// ---------------- f32 -> bf16 elementwise, 8/thread ----------------
__global__ __launch_bounds__(256) void cvt_bf16_v(const float* __restrict__ X,
                                                  __hip_bfloat16* __restrict__ Y) {
  int i = (blockIdx.x * 256 + threadIdx.x) * 8;
  float4 v0 = *(const float4*)(X + i);
  float4 v1 = *(const float4*)(X + i + 4);
  float v[8] = {v0.x, v0.y, v0.z, v0.w, v1.x, v1.y, v1.z, v1.w};
  __hip_bfloat16 o[8];
#pragma unroll
  for (int j = 0; j < 8; ++j) o[j] = __float2bfloat16(v[j]);
  *(vshort8*)&Y[i] = *(vshort8*)o;
}

// ---------------- batched f32 -> bf16 transposes (one launch for all weights) ----------------
struct TD {
  const float* src;
  __hip_bfloat16* dst;
  int K, N;       // src is K x N; dst is N x K
  float scale;
  int base;       // first 32x32 tile index for this entry
};
struct TDArr { TD d[11]; };

__global__ __launch_bounds__(256) void transpose_batch(TDArr a) {
  __shared__ float tile[32][33];
  int b = blockIdx.x;
  int e = 0;
#pragma unroll
  for (int i = 1; i < 11; ++i)
    if (b >= a.d[i].base) e = i;
  TD t = a.d[e];
  int lt = b - t.base;
  int ntn = t.N >> 5;
  int n0 = (lt % ntn) * 32, k0 = (lt / ntn) * 32;
  int tx = threadIdx.x & 31, ty = threadIdx.x >> 5;
  for (int r = ty; r < 32; r += 8) tile[r][tx] = t.src[(size_t)(k0 + r) * t.N + n0 + tx];
  __syncthreads();
  for (int r = ty; r < 32; r += 8)
    t.dst[(size_t)(n0 + r) * t.K + k0 + tx] = __float2bfloat16(tile[tx][r] * t.scale);
}

// ---------------- skinny bf16 MFMA GEMM (gload16): M=64, tile 64x128, split-K ----------------
__global__ __launch_bounds__(256) void mfma_skinny(const __hip_bfloat16* __restrict__ A,
                                                   const __hip_bfloat16* __restrict__ Bt,
                                                   float* __restrict__ part,
                                                   int N, int K, int lda, int Kc) {
  __shared__ short AS[64 * 32];   // 4 KB linear
  __shared__ short BS[128 * 32];  // 8 KB linear
  int t = threadIdx.x;
  int lane = t & 63, wv = t >> 6;
  int n0 = blockIdx.x * 128;
  int kbeg = blockIdx.y * Kc;
  int wn = wv * 32;
  int lrow = lane & 15, kb = (lane >> 4) * 8;
  vfloat4 acc[4][2];
#pragma unroll
  for (int i = 0; i < 4; ++i)
#pragma unroll
    for (int j = 0; j < 2; ++j) acc[i][j] = (vfloat4){0.f, 0.f, 0.f, 0.f};
  const short* Ag = (const short*)A;
  const short* Bg = (const short*)Bt;
  int arow = lane >> 2;        // 0..15
  int acol = (lane & 3) * 8;   // shorts
  for (int k0 = kbeg; k0 < kbeg + Kc; k0 += 32) {
    gload16(Ag + (size_t)(wv * 16 + arow) * lda + k0 + acol, &AS[(wv * 16) * 32]);
#pragma unroll
    for (int c = 0; c < 2; ++c)
      gload16(Bg + (size_t)(n0 + c * 64 + wv * 16 + arow) * K + k0 + acol,
              &BS[(c * 64 + wv * 16) * 32]);
    __syncthreads();
    vbf16x8 af[4], bq[2];
#pragma unroll
    for (int i = 0; i < 4; ++i) af[i] = *(const vbf16x8*)&AS[(i * 16 + lrow) * 32 + kb];
#pragma unroll
    for (int j = 0; j < 2; ++j) bq[j] = *(const vbf16x8*)&BS[(wn + j * 16 + lrow) * 32 + kb];
#pragma unroll
    for (int i = 0; i < 4; ++i)
#pragma unroll
      for (int j = 0; j < 2; ++j)
        acc[i][j] = __builtin_amdgcn_mfma_f32_16x16x32_bf16(af[i], bq[j], acc[i][j], 0, 0, 0);
    __syncthreads();
  }
  size_t zbase = (size_t)blockIdx.y * 64;
  int crow0 = (lane >> 4) * 4;
  int ccol0 = n0 + wn + lrow;
#pragma unroll
  for (int i = 0; i < 4; ++i) {
#pragma unroll
    for (int j = 0; j < 2; ++j) {
      int col = ccol0 + j * 16;
#pragma unroll
      for (int r = 0; r < 4; ++r) {
        int rowi = i * 16 + crow0 + r;
        part[(zbase + rowi) * N + col] = acc[i][j][r];
      }
    }
  }
}

// ---------------- C[64][N] = sum_z part[z][64][N] + bias (opt. bf16 copy) ----------------
template <bool BF16OUT>
__global__ __launch_bounds__(256) void reduce_bias(const float* __restrict__ part,
                                                   const float* __restrict__ bias,
                                                   float* __restrict__ C,
                                                   __hip_bfloat16* __restrict__ Cb,
                                                   int N, int SK) {
  int i = blockIdx.x * 256 + threadIdx.x;  // < 64*N
  int col = i & (N - 1);                   // N is a power of two
  float s = bias[col];
  for (int z = 0; z < SK; ++z) s += part[(size_t)z * 64 * N + i];
  C[i] = s;
  if (BF16OUT) Cb[i] = __float2bfloat16(s);
}

// ---------------- combined cterm reduce: out[64][4096], bias = [rn_b1 | en_b1] ----------------
__global__ __launch_bounds__(256) void reduce_cterm(const float* __restrict__ part,
                                                    const float* __restrict__ rn_b1,
                                                    const float* __restrict__ en_b1,
                                                    float* __restrict__ out, int SK) {
  int i = blockIdx.x * 256 + threadIdx.x;  // < 64*4096
  int col = i & 4095;
  float s = (col < 2048) ? rn_b1[col] : en_b1[col - 2048];
  for (int z = 0; z < SK; ++z) s += part[(size_t)z * 64 * 4096 + i];
  out[i] = s;
}

// ---------------- fused split-K reduce + LayerNorm(2048) + relu -> bf16 (64 rows) ----------------
__global__ __launch_bounds__(256) void ln2048red(const float* __restrict__ part,
                                                 const float* __restrict__ bias,
                                                 const float* __restrict__ g,
                                                 const float* __restrict__ be,
                                                 __hip_bfloat16* __restrict__ out, int SK) {
  __shared__ float red[256];
  int row = blockIdx.x, t = threadIdx.x;
  int j0 = t * 8;
  float v[8];
  *(float4*)&v[0] = *(const float4*)(bias + j0);
  *(float4*)&v[4] = *(const float4*)(bias + j0 + 4);
  for (int z = 0; z < SK; ++z) {
    const float* p = part + (size_t)z * 64 * 2048 + (size_t)row * 2048 + j0;
    float4 a0 = *(const float4*)p, a1 = *(const float4*)(p + 4);
    v[0] += a0.x; v[1] += a0.y; v[2] += a0.z; v[3] += a0.w;
    v[4] += a1.x; v[5] += a1.y; v[6] += a1.z; v[7] += a1.w;
  }
  float s = 0.f;
#pragma unroll
  for (int j = 0; j < 8; ++j) s += v[j];
  red[t] = s; __syncthreads();
  for (int k = 128; k > 0; k >>= 1) { if (t < k) red[t] += red[t + k]; __syncthreads(); }
  float mean = red[0] * (1.0f / 2048.0f);
  __syncthreads();
  float s2 = 0.f;
#pragma unroll
  for (int j = 0; j < 8; ++j) { float d = v[j] - mean; s2 += d * d; }
  red[t] = s2; __syncthreads();
  for (int k = 128; k > 0; k >>= 1) { if (t < k) red[t] += red[t + k]; __syncthreads(); }
  float rstd = rsqrtf(red[0] * (1.0f / 2048.0f) + 1e-5f);
  __hip_bfloat16 o[8];
#pragma unroll
  for (int j = 0; j < 8; ++j) {
    float y = (v[j] - mean) * rstd * g[j0 + j] + be[j0 + j];
    o[j] = __float2bfloat16(fmaxf(y, 0.f));
  }
  *(vshort8*)&out[(size_t)row * 2048 + j0] = *(vshort8*)o;
}

// ---------------- combine (bf16 G) + LayerNorm + relu -> bf16 ----------------
// NEIGH=1: v = G[row][j] + G[prow][2048+j] + G[nrow][2048+j] + cterm[b][j] (G stride 4096)
// NEIGH=0: v = G[row][j] + cterm[b][j]                                    (G stride 2048)
template <int NEIGH>
__global__ __launch_bounds__(256) void ln_comb(const __hip_bfloat16* __restrict__ G,
                                               const float* __restrict__ cterm, int cstride,
                                               const float* __restrict__ g,
                                               const float* __restrict__ be,
                                               __hip_bfloat16* __restrict__ out) {
  __shared__ float red[256];
  int row = blockIdx.x, t = threadIdx.x;
  int j0 = t * 8;
  const int GS = NEIGH ? 4096 : 2048;
  float v[8];
  load_bf8(G + (size_t)row * GS + j0, v);
  {
    const float* p = cterm + (size_t)(row >> 5) * cstride + j0;
    float4 a0 = *(const float4*)p, a1 = *(const float4*)(p + 4);
    v[0] += a0.x; v[1] += a0.y; v[2] += a0.z; v[3] += a0.w;
    v[4] += a1.x; v[5] += a1.y; v[6] += a1.z; v[7] += a1.w;
  }
  if (NEIGH) {
    int f = row & 7;
    int prow = (f == 0) ? row : row - 1;
    int nrow = (f == NF_ - 1) ? row : row + 1;
    float a[8], b[8];
    load_bf8(G + (size_t)prow * 4096 + 2048 + j0, a);
    load_bf8(G + (size_t)nrow * 4096 + 2048 + j0, b);
#pragma unroll
    for (int j = 0; j < 8; ++j) v[j] += a[j] + b[j];
  }
  float s = 0.f;
#pragma unroll
  for (int j = 0; j < 8; ++j) s += v[j];
  red[t] = s; __syncthreads();
  for (int k = 128; k > 0; k >>= 1) { if (t < k) red[t] += red[t + k]; __syncthreads(); }
  float mean = red[0] * (1.0f / 2048.0f);
  __syncthreads();
  float s2 = 0.f;
#pragma unroll
  for (int j = 0; j < 8; ++j) { float d = v[j] - mean; s2 += d * d; }
  red[t] = s2; __syncthreads();
  for (int k = 128; k > 0; k >>= 1) { if (t < k) red[t] += red[t + k]; __syncthreads(); }
  float rstd = rsqrtf(red[0] * (1.0f / 2048.0f) + 1e-5f);
  __hip_bfloat16 o[8];
#pragma unroll
  for (int j = 0; j < 8; ++j) {
    float y = (v[j] - mean) * rstd * g[j0 + j] + be[j0 + j];
    o[j] = __float2bfloat16(fmaxf(y, 0.f));
  }
  *(vshort8*)&out[(size_t)row * 2048 + j0] = *(vshort8*)o;
}

// ---------------- bf16 MFMA GEMM via global_load_lds, BK=64 ----------------
// tile: 128(M) x 64(N), 4 waves (2x2), acc[4][2].
// MODE 1: bias+relu (f32 out); MODE 2: fused x-update + bf16 x copy; MODE 4: raw bf16 out
template <int MODE>
__global__ __launch_bounds__(256) void gemm_gl(const __hip_bfloat16* __restrict__ A,
                                               const __hip_bfloat16* __restrict__ Bt,
                                               const float* __restrict__ bias,
                                               float* __restrict__ Cout,
                                               __hip_bfloat16* __restrict__ Cbout,
                                               int M, int N, int K, int it) {
  __shared__ short Als[128 * 64];  // 16 KB linear
  __shared__ short Bls[64 * 64];   // 8 KB linear
  int t = threadIdx.x;
  int lane = t & 63, wv = t >> 6;
  int n0 = blockIdx.x * 64, m0 = blockIdx.y * 128;
  int wm = (wv >> 1) * 64, wn = (wv & 1) * 32;
  int lrow = lane & 15, kb = (lane >> 4) * 8;
  vfloat4 acc[4][2];
#pragma unroll
  for (int i = 0; i < 4; ++i)
#pragma unroll
    for (int j = 0; j < 2; ++j) acc[i][j] = (vfloat4){0.f, 0.f, 0.f, 0.f};
  const short* Ag = (const short*)A;
  const short* Bg = (const short*)Bt;
  int arow = lane >> 3;        // 0..7 (8 lanes per 128B row)
  int acol = (lane & 7) * 8;   // shorts
  for (int k0 = 0; k0 < K; k0 += 64) {
#pragma unroll
    for (int c = 0; c < 4; ++c)
      gload16(Ag + (size_t)(m0 + c * 32 + wv * 8 + arow) * K + k0 + acol,
              &Als[(c * 32 + wv * 8) * 64]);
#pragma unroll
    for (int c = 0; c < 2; ++c)
      gload16(Bg + (size_t)(n0 + c * 32 + wv * 8 + arow) * K + k0 + acol,
              &Bls[(c * 32 + wv * 8) * 64]);
    __syncthreads();
    vbf16x8 af[2][4], bq[2][2];
#pragma unroll
    for (int ks = 0; ks < 2; ++ks) {
#pragma unroll
      for (int i = 0; i < 4; ++i)
        af[ks][i] = *(const vbf16x8*)&Als[(wm + i * 16 + lrow) * 64 + ks * 32 + kb];
#pragma unroll
      for (int j = 0; j < 2; ++j)
        bq[ks][j] = *(const vbf16x8*)&Bls[(wn + j * 16 + lrow) * 64 + ks * 32 + kb];
    }
#pragma unroll
    for (int ks = 0; ks < 2; ++ks)
#pragma unroll
      for (int i = 0; i < 4; ++i)
#pragma unroll
        for (int j = 0; j < 2; ++j)
          acc[i][j] = __builtin_amdgcn_mfma_f32_16x16x32_bf16(af[ks][i], bq[ks][j], acc[i][j], 0, 0, 0);
    __syncthreads();
  }
  int crow0 = m0 + wm + (lane >> 4) * 4;
  int ccol0 = n0 + wn + lrow;
  if (MODE == 2) {
    uint32_t key0 = 0, key1 = 0;
    bool addn = (it < NIT_ - 1);
    if (addn) threefry2x32(0u, 7u, 0u, (uint32_t)it, key0, key1);  // fold_in(key(7), it)
#pragma unroll
    for (int i = 0; i < 4; ++i) {
#pragma unroll
      for (int j = 0; j < 2; ++j) {
        int col = ccol0 + j * 16;
        float bv = bias[col];
#pragma unroll
        for (int r = 0; r < 4; ++r) {
          uint32_t idx = (uint32_t)(crow0 + i * 16 + r) * N + col;
          float xv = Cout[idx] - 0.1f * (acc[i][j][r] + bv);
          if (addn) xv += 0.01f * bits_to_normal(tf_bits_part(key0, key1, idx));
          Cout[idx] = xv;
          Cbout[idx] = __float2bfloat16(xv);
        }
      }
    }
  } else if (MODE == 4) {
#pragma unroll
    for (int i = 0; i < 4; ++i) {
#pragma unroll
      for (int j = 0; j < 2; ++j) {
        int col = ccol0 + j * 16;
#pragma unroll
        for (int r = 0; r < 4; ++r)
          Cbout[(size_t)(crow0 + i * 16 + r) * N + col] = __float2bfloat16(acc[i][j][r]);
      }
    }
  } else {
#pragma unroll
    for (int i = 0; i < 4; ++i) {
#pragma unroll
      for (int j = 0; j < 2; ++j) {
        int col = ccol0 + j * 16;
        float bv = bias[col];
#pragma unroll
        for (int r = 0; r < 4; ++r) {
          float v = acc[i][j][r] + bv;
          if (MODE == 1) v = fmaxf(v, 0.f);
          Cout[(size_t)(crow0 + i * 16 + r) * N + col] = v;
        }
      }
    }
  }
}

// ---------------- fused: traj = reduce(part)+bias; x[b,h] = traj + 0.1*normal ----------------
__global__ __launch_bounds__(256) void reduce_traj_noise(const float* __restrict__ part,
                                                         const float* __restrict__ bias,
                                                         float* __restrict__ x,
                                                         __hip_bfloat16* __restrict__ xb,
                                                         int SK) {
  int i = blockIdx.x * 256 + threadIdx.x;  // < 524288 (traj index)
  int fe = i & 8191;
  float s = bias[fe];
  for (int z = 0; z < SK; ++z) s += part[(size_t)z * 524288 + i];
  int b = i >> 13;
#pragma unroll
  for (int h = 0; h < NH_; ++h) {
    uint32_t xi = (uint32_t)(b * 32768 + h * 8192 + fe);
    float xv = s + 0.1f * bits_to_normal(tf_bits_part(0u, 42u, xi));
    x[xi] = xv;
    xb[xi] = __float2bfloat16(xv);
  }
}

// ---------------- per-row dot with en_w3 ----------------
__global__ __launch_bounds__(256) void rowdot(const float* __restrict__ X2,
                                              const float* __restrict__ w3,
                                              const float* __restrict__ b3,
                                              float* __restrict__ srow) {
  __shared__ float red[256];
  int row = blockIdx.x, t = threadIdx.x;
  const float* xr = X2 + (size_t)row * E_;
  float s = 0.f;
  for (int c = t; c < E_; c += 256) s += xr[c] * w3[c];
  red[t] = s; __syncthreads();
  for (int k = 128; k > 0; k >>= 1) { if (t < k) red[t] += red[t + k]; __syncthreads(); }
  if (t == 0) srow[row] = red[0] + b3[0];
}

// ---------------- energies[bh] = coherence + 0.1*smoothness + supervision ----------------
__global__ __launch_bounds__(256) void energy_final(const float* __restrict__ x,
                                                    const float* __restrict__ ft,
                                                    const float* __restrict__ srow,
                                                    float* __restrict__ energ) {
  __shared__ float red[256];
  int bh = blockIdx.x, t = threadIdx.x;
  int b = bh >> 2;
  const float* xb = x + (size_t)bh * (NF_ * E_);
  const float* fb = ft + (size_t)b * (NF_ * E_);
  float sup = 0.f;
  for (int i = t; i < NF_ * E_; i += 256) { float d = xb[i] - fb[i]; sup += d * d; }
  red[t] = sup; __syncthreads();
  for (int k = 128; k > 0; k >>= 1) { if (t < k) red[t] += red[t + k]; __syncthreads(); }
  float supervision = red[0] / (NF_ * E_);
  float smooth = 0.f;
  for (int d = 0; d < NF_ - 1; ++d) {
    __syncthreads();
    float sd = 0.f;
    for (int e = t; e < E_; e += 256) {
      float df = xb[(d + 1) * E_ + e] - xb[d * E_ + e];
      sd += df * df;
    }
    red[t] = sd; __syncthreads();
    for (int k = 128; k > 0; k >>= 1) { if (t < k) red[t] += red[t + k]; __syncthreads(); }
    smooth += sqrtf(red[0]);
  }
  smooth *= (1.0f / (NF_ - 1));
  if (t == 0) {
    float coh = 0.f;
    for (int f = 0; f < NF_; ++f) coh += srow[bh * NF_ + f];
    coh *= (1.0f / NF_);
    energ[bh] = coh + 0.1f * smooth + supervision;
  }
}

__global__ void softmax_probs(const float* __restrict__ energ, float* __restrict__ probs) {
  int b = threadIdx.x;
  if (b < B_) {
    float e[NH_], m = -1e30f;
#pragma unroll
    for (int h = 0; h < NH_; ++h) { e[h] = -energ[b * NH_ + h]; m = fmaxf(m, e[h]); }
    float s = 0.f, p[NH_];
#pragma unroll
    for (int h = 0; h < NH_; ++h) { p[h] = expf(e[h] - m); s += p[h]; }
#pragma unroll
    for (int h = 0; h < NH_; ++h) probs[b * NH_ + h] = p[h] / s;
  }
}

__global__ __launch_bounds__(256) void predict(const float* __restrict__ x,
                                               const float* __restrict__ probs,
                                               float* __restrict__ out) {
  int i = blockIdx.x * 256 + threadIdx.x;  // < 524288
  int b = i >> 13, fe = i & 8191;
  float s = 0.f;
#pragma unroll
  for (int h = 0; h < NH_; ++h) s += x[(size_t)(b * NH_ + h) * 8192 + fe] * probs[b * NH_ + h];
  out[i] = s;
}

extern "C" void kernel_launch(void* const* d_in, const int* in_sizes, int n_in,
                              void* d_out, int out_size, void* d_ws, size_t ws_size,
                              hipStream_t stream) {
  const float* cur   = (const float*)d_in[0];
  const float* ftrue = (const float*)d_in[1];
  const float* ce_w1 = (const float*)d_in[2];
  const float* ce_b1 = (const float*)d_in[3];
  const float* ce_g  = (const float*)d_in[4];
  const float* ce_be = (const float*)d_in[5];
  const float* ce_w2 = (const float*)d_in[6];
  const float* ce_b2 = (const float*)d_in[7];
  const float* tp_w1 = (const float*)d_in[8];
  const float* tp_b1 = (const float*)d_in[9];
  const float* tp_g  = (const float*)d_in[10];
  const float* tp_be = (const float*)d_in[11];
  const float* tp_w2 = (const float*)d_in[12];
  const float* tp_b2 = (const float*)d_in[13];
  const float* en_w1 = (const float*)d_in[14];
  const float* en_b1 = (const float*)d_in[15];
  const float* en_g  = (const float*)d_in[16];
  const float* en_be = (const float*)d_in[17];
  const float* en_w2 = (const float*)d_in[18];
  const float* en_b2 = (const float*)d_in[19];
  const float* en_w3 = (const float*)d_in[20];
  const float* en_b3 = (const float*)d_in[21];
  const float* rn_w1 = (const float*)d_in[22];
  const float* rn_b1 = (const float*)d_in[23];
  const float* rn_g  = (const float*)d_in[24];
  const float* rn_be = (const float*)d_in[25];
  const float* rn_w2 = (const float*)d_in[26];
  const float* rn_b2 = (const float*)d_in[27];
  (void)in_sizes; (void)n_in; (void)out_size; (void)ws_size;

  char* w = (char*)d_ws;
  size_t off = 0;
  auto alloc = [&](size_t bytes) -> void* {
    void* p = w + off;
    off += (bytes + 255) & ~(size_t)255;
    return p;
  };
  float* part   = (float*)alloc((size_t)8 * B_ * E_ * 4);
  float* ctx    = (float*)alloc((size_t)B_ * E_ * 4);
  float* g1     = (float*)alloc((size_t)B_ * H_ * 4);
  float* x      = (float*)alloc((size_t)2097152 * 4);
  float* skpart = (float*)alloc((size_t)8 * 64 * 8192 * 4);  // 16.78 MB split-K partials
  __hip_bfloat16* Gb = (__hip_bfloat16*)alloc((size_t)2048 * 4096 * 2);  // big-GEMM output (bf16)
  float* u      = (float*)alloc((size_t)2048 * 1024 * 4);
  __hip_bfloat16* ub   = (__hip_bfloat16*)alloc((size_t)2048 * 2048 * 2);
  __hip_bfloat16* x_b  = (__hip_bfloat16*)alloc((size_t)2048 * 1024 * 2);
  float* srow   = (float*)alloc((size_t)2048 * 4);
  float* energ  = (float*)alloc((size_t)256 * 4);
  float* probs  = (float*)alloc((size_t)256 * 4);
  float* ctermcat = (float*)alloc((size_t)B_ * 4096 * 4);  // [cterm | ecterm]
  __hip_bfloat16* Wcat_t  = (__hip_bfloat16*)alloc((size_t)4096 * 1024 * 2);  // [W1a; 0.5*W1c]^T
  __hip_bfloat16* Wbcat_t = (__hip_bfloat16*)alloc((size_t)4096 * 1024 * 2);  // [W1b; en_w1b]^T
  __hip_bfloat16* rn_w2t = (__hip_bfloat16*)alloc((size_t)1024 * 2048 * 2);
  __hip_bfloat16* en1a_t = (__hip_bfloat16*)alloc((size_t)2048 * 1024 * 2);
  __hip_bfloat16* en_w2t = (__hip_bfloat16*)alloc((size_t)1024 * 2048 * 2);
  __hip_bfloat16* ctx_b  = (__hip_bfloat16*)alloc((size_t)B_ * E_ * 2);
  __hip_bfloat16* ctxh_b = (__hip_bfloat16*)alloc((size_t)B_ * H_ * 2);
  __hip_bfloat16* lnb    = (__hip_bfloat16*)alloc((size_t)B_ * H_ * 2);
  __hip_bfloat16* cw1t = (__hip_bfloat16*)alloc((size_t)2048 * 1024 * 2);
  __hip_bfloat16* cw2t = (__hip_bfloat16*)alloc((size_t)2048 * 2048 * 2);
  __hip_bfloat16* tw1t = (__hip_bfloat16*)alloc((size_t)2048 * 2048 * 2);
  __hip_bfloat16* tw2t = (__hip_bfloat16*)alloc((size_t)8192 * 2048 * 2);

  // ctx = mean_S
  colmean_partial<<<512, 256, 0, stream>>>(cur, part);
  colmean_final<<<256, 256, 0, stream>>>(part, ctx);

  // weight prep: ONE batched transpose launch (11 descriptors, 40960 tiles)
  TDArr ta;
  int base = 0;
  auto set = [&](int idx, const float* src, __hip_bfloat16* dst, int K, int N, float sc) {
    ta.d[idx] = TD{src, dst, K, N, sc, base};
    base += (N >> 5) * (K >> 5);
  };
  set(0, rn_w1, Wcat_t, 1024, 2048, 1.0f);
  set(1, rn_w1 + (size_t)2048 * 2048, Wcat_t + (size_t)2048 * 1024, 1024, 2048, 0.5f);
  set(2, rn_w1 + (size_t)1024 * 2048, Wbcat_t, 1024, 2048, 1.0f);
  set(3, en_w1 + (size_t)1024 * 2048, Wbcat_t + (size_t)2048 * 1024, 1024, 2048, 1.0f);
  set(4, rn_w2, rn_w2t, 2048, 1024, 1.0f);
  set(5, en_w1, en1a_t, 1024, 2048, 1.0f);
  set(6, en_w2, en_w2t, 2048, 1024, 1.0f);
  set(7, ce_w1, cw1t, 1024, 2048, 1.0f);
  set(8, ce_w2, cw2t, 2048, 2048, 1.0f);
  set(9, tp_w1, tw1t, 2048, 2048, 1.0f);
  set(10, tp_w2, tw2t, 2048, 8192, 1.0f);
  transpose_batch<<<base, 256, 0, stream>>>(ta);

  // ---- context/trajectory path (plain bf16 skinny GEMMs, M=64) ----
  cvt_bf16_v<<<32, 256, 0, stream>>>(ctx, ctx_b);
  mfma_skinny<<<dim3(16, 4), 256, 0, stream>>>(ctx_b, cw1t, skpart, 2048, 1024, 1024, 256);
  ln2048red<<<B_, 256, 0, stream>>>(skpart, ce_b1, ce_g, ce_be, lnb, 4);
  mfma_skinny<<<dim3(16, 8), 256, 0, stream>>>(lnb, cw2t, skpart, 2048, 2048, 2048, 256);
  reduce_bias<true><<<512, 256, 0, stream>>>(skpart, ce_b2, g1, ctxh_b, 2048, 8);
  mfma_skinny<<<dim3(16, 8), 256, 0, stream>>>(ctxh_b, tw1t, skpart, 2048, 2048, 2048, 256);
  ln2048red<<<B_, 256, 0, stream>>>(skpart, tp_b1, tp_g, tp_be, lnb, 8);
  mfma_skinny<<<dim3(64, 8), 256, 0, stream>>>(lnb, tw2t, skpart, 8192, 2048, 2048, 256);
  reduce_traj_noise<<<2048, 256, 0, stream>>>(skpart, tp_b2, x, x_b, 8);

  // constant terms (once): [cterm | ecterm] = ce @ [W1b | en_w1b] + [rn_b1 | en_b1]
  mfma_skinny<<<dim3(32, 4), 256, 0, stream>>>(ctxh_b, Wbcat_t, skpart, 4096, 1024, 2048, 256);
  reduce_cterm<<<1024, 256, 0, stream>>>(skpart, rn_b1, en_b1, ctermcat, 4);

  // refinement loop: 3 dispatches/iter
  for (int it = 0; it < NIT_; ++it) {
    gemm_gl<4><<<dim3(64, 16), 256, 0, stream>>>(x_b, Wcat_t, nullptr, nullptr, Gb,
                                                 2048, 4096, 1024, 0);
    ln_comb<1><<<2048, 256, 0, stream>>>(Gb, ctermcat, 4096, rn_g, rn_be, ub);
    gemm_gl<2><<<dim3(16, 16), 256, 0, stream>>>(ub, rn_w2t, rn_b2, x, x_b,
                                                 2048, 1024, 2048, it);
  }

  // energy + softmax + weighted prediction
  gemm_gl<4><<<dim3(32, 16), 256, 0, stream>>>(x_b, en1a_t, nullptr, nullptr, Gb,
                                               2048, 2048, 1024, 0);
  ln_comb<0><<<2048, 256, 0, stream>>>(Gb, ctermcat + 2048, 4096, en_g, en_be, ub);
  gemm_gl<1><<<dim3(16, 16), 256, 0, stream>>>(ub, en_w2t, en_b2, u, nullptr,
                                               2048, 1024, 2048, 0);
  rowdot<<<2048, 256, 0, stream>>>(u, en_w3, en_b3, srow);
  energy_final<<<256, 256, 0, stream>>>(x, ftrue, srow, energ);
  softmax_probs<<<1, 64, 0, stream>>>(energ, probs);
  predict<<<2048, 256, 0, stream>>>(x, probs, (float*)d_out);
}

// Round 12
// 1083.736 us; speedup vs baseline: 1.3749x; 1.2144x over previous
//
#include <hip/hip_runtime.h>
#include <hip/hip_bf16.h>
#include <stdint.h>

#define B_ 64
#define S_ 1024
#define E_ 1024
#define H_ 2048
#define NF_ 8
#define NH_ 4
#define NIT_ 10

typedef __attribute__((ext_vector_type(8))) short vshort8;
typedef __attribute__((ext_vector_type(8))) __bf16 vbf16x8;
typedef __attribute__((ext_vector_type(4))) float vfloat4;

// ---------------- async global->LDS, 16B per lane ----------------
typedef const __attribute__((address_space(1))) void* gas1_t;
typedef __attribute__((address_space(3))) void* las3_t;
__device__ __forceinline__ void gload16(const void* g, void* l) {
  __builtin_amdgcn_global_load_lds((gas1_t)g, (las3_t)l, 16, 0, 0);
}

// ---------------- threefry2x32 (JAX-exact) ----------------
__device__ __forceinline__ uint32_t rotl32(uint32_t v, int n) { return (v << n) | (v >> (32 - n)); }

__device__ __forceinline__ void threefry2x32(uint32_t k0, uint32_t k1, uint32_t x0, uint32_t x1,
                                             uint32_t& o0, uint32_t& o1) {
  uint32_t ks2 = k0 ^ k1 ^ 0x1BD11BDAu;
  x0 += k0; x1 += k1;
#define TF_R(r) { x0 += x1; x1 = rotl32(x1, (r)); x1 ^= x0; }
  TF_R(13) TF_R(15) TF_R(26) TF_R(6)
  x0 += k1;  x1 += ks2 + 1u;
  TF_R(17) TF_R(29) TF_R(16) TF_R(24)
  x0 += ks2; x1 += k0 + 2u;
  TF_R(13) TF_R(15) TF_R(26) TF_R(6)
  x0 += k0;  x1 += k1 + 3u;
  TF_R(17) TF_R(29) TF_R(16) TF_R(24)
  x0 += k1;  x1 += ks2 + 4u;
  TF_R(13) TF_R(15) TF_R(26) TF_R(6)
  x0 += ks2; x1 += k0 + 5u;
#undef TF_R
  o0 = x0; o1 = x1;
}

// partitionable threefry 32-bit bits: element i -> bits1 ^ bits2 of threefry(key, (0, i))
__device__ __forceinline__ uint32_t tf_bits_part(uint32_t k0, uint32_t k1, uint32_t i) {
  uint32_t o0, o1;
  threefry2x32(k0, k1, 0u, i, o0, o1);
  return o0 ^ o1;
}

// XLA/Giles erfinv (f32)
__device__ __forceinline__ float erfinv_f(float x) {
  float w = -log1pf(-x * x);
  float p;
  if (w < 5.0f) {
    w -= 2.5f;
    p = 2.81022636e-08f;
    p = 3.43273939e-07f + p * w;
    p = -3.5233877e-06f + p * w;
    p = -4.39150654e-06f + p * w;
    p = 0.00021858087f + p * w;
    p = -0.00125372503f + p * w;
    p = -0.00417768164f + p * w;
    p = 0.246640727f + p * w;
    p = 1.50140941f + p * w;
  } else {
    w = sqrtf(w) - 3.0f;
    p = -0.000200214257f;
    p = 0.000100950558f + p * w;
    p = 0.00134934322f + p * w;
    p = -0.00367342844f + p * w;
    p = 0.00573950773f + p * w;
    p = -0.0076224613f + p * w;
    p = 0.00943887047f + p * w;
    p = 1.00167406f + p * w;
    p = 2.83297682f + p * w;
  }
  return p * x;
}

__device__ __forceinline__ float bits_to_normal(uint32_t bits) {
  uint32_t fb = (bits >> 9) | 0x3F800000u;
  float f = __uint_as_float(fb) - 1.0f;       // [0,1)
  const float lo = -0.99999994f;              // nextafter(-1,0)
  float u = fmaxf(lo, f * 2.0f + lo);
  return 1.41421356f * erfinv_f(u);
}

__device__ __forceinline__ void load_bf8(const __hip_bfloat16* p, float v[8]) {
  vshort8 s = *(const vshort8*)p;
#pragma unroll
  for (int j = 0; j < 8; ++j) {
    uint32_t b = ((uint32_t)(uint16_t)s[j]) << 16;
    v[j] = __uint_as_float(b);
  }
}

// ---------------- ctx = mean over S ----------------
__global__ __launch_bounds__(256) void colmean_partial(const float* __restrict__ cur,
                                                       float* __restrict__ part) {
  int blk = blockIdx.x;            // 512 blocks: b*8 + chunk
  int b = blk >> 3, c = blk & 7;
  int t = threadIdx.x;
  const float* base = cur + ((size_t)b * S_ + (size_t)c * 128) * E_;
  float4 s = {0.f, 0.f, 0.f, 0.f};
  for (int si = 0; si < 128; ++si) {
    float4 v = *(const float4*)(base + (size_t)si * E_ + t * 4);
    s.x += v.x; s.y += v.y; s.z += v.z; s.w += v.w;
  }
  *(float4*)(part + ((size_t)c * B_ + b) * E_ + t * 4) = s;
}

__global__ __launch_bounds__(256) void colmean_final_bf(const float* __restrict__ part,
                                                        __hip_bfloat16* __restrict__ ctxb) {
  int i = blockIdx.x * 256 + threadIdx.x;  // < 65536
  float s = 0.f;
#pragma unroll
  for (int c = 0; c < 8; ++c) s += part[(size_t)c * (B_ * E_) + i];
  ctxb[i] = __float2bfloat16(s * (1.0f / S_));
}

// ---------------- batched f32 -> bf16 transposes (one launch for all weights) ----------------
struct TD {
  const float* src;
  __hip_bfloat16* dst;
  int K, N;       // src is K x N; dst is N x K
  float scale;
  int base;       // first 32x32 tile index for this entry
};
struct TDArr { TD d[11]; };

__global__ __launch_bounds__(256) void transpose_batch(TDArr a) {
  __shared__ float tile[32][33];
  int b = blockIdx.x;
  int e = 0;
#pragma unroll
  for (int i = 1; i < 11; ++i)
    if (b >= a.d[i].base) e = i;
  TD t = a.d[e];
  int lt = b - t.base;
  int ntn = t.N >> 5;
  int n0 = (lt % ntn) * 32, k0 = (lt / ntn) * 32;
  int tx = threadIdx.x & 31, ty = threadIdx.x >> 5;
  for (int r = ty; r < 32; r += 8) tile[r][tx] = t.src[(size_t)(k0 + r) * t.N + n0 + tx];
  __syncthreads();
  for (int r = ty; r < 32; r += 8)
    t.dst[(size_t)(n0 + r) * t.K + k0 + tx] = __float2bfloat16(tile[tx][r] * t.scale);
}

// ---------------- skinny bf16 MFMA GEMM (gload16): M=64, tile 64x128, split-K ----------------
__global__ __launch_bounds__(256) void mfma_skinny(const __hip_bfloat16* __restrict__ A,
                                                   const __hip_bfloat16* __restrict__ Bt,
                                                   float* __restrict__ part,
                                                   int N, int K, int lda, int Kc) {
  __shared__ short AS[64 * 32];   // 4 KB linear
  __shared__ short BS[128 * 32];  // 8 KB linear
  int t = threadIdx.x;
  int lane = t & 63, wv = t >> 6;
  int n0 = blockIdx.x * 128;
  int kbeg = blockIdx.y * Kc;
  int wn = wv * 32;
  int lrow = lane & 15, kb = (lane >> 4) * 8;
  vfloat4 acc[4][2];
#pragma unroll
  for (int i = 0; i < 4; ++i)
#pragma unroll
    for (int j = 0; j < 2; ++j) acc[i][j] = (vfloat4){0.f, 0.f, 0.f, 0.f};
  const short* Ag = (const short*)A;
  const short* Bg = (const short*)Bt;
  int arow = lane >> 2;        // 0..15
  int acol = (lane & 3) * 8;   // shorts
  for (int k0 = kbeg; k0 < kbeg + Kc; k0 += 32) {
    gload16(Ag + (size_t)(wv * 16 + arow) * lda + k0 + acol, &AS[(wv * 16) * 32]);
#pragma unroll
    for (int c = 0; c < 2; ++c)
      gload16(Bg + (size_t)(n0 + c * 64 + wv * 16 + arow) * K + k0 + acol,
              &BS[(c * 64 + wv * 16) * 32]);
    __syncthreads();
    vbf16x8 af[4], bq[2];
#pragma unroll
    for (int i = 0; i < 4; ++i) af[i] = *(const vbf16x8*)&AS[(i * 16 + lrow) * 32 + kb];
#pragma unroll
    for (int j = 0; j < 2; ++j) bq[j] = *(const vbf16x8*)&BS[(wn + j * 16 + lrow) * 32 + kb];
#pragma unroll
    for (int i = 0; i < 4; ++i)
#pragma unroll
      for (int j = 0; j < 2; ++j)
        acc[i][j] = __builtin_amdgcn_mfma_f32_16x16x32_bf16(af[i], bq[j], acc[i][j], 0, 0, 0);
    __syncthreads();
  }
  size_t zbase = (size_t)blockIdx.y * 64;
  int crow0 = (lane >> 4) * 4;
  int ccol0 = n0 + wn + lrow;
#pragma unroll
  for (int i = 0; i < 4; ++i) {
#pragma unroll
    for (int j = 0; j < 2; ++j) {
      int col = ccol0 + j * 16;
#pragma unroll
      for (int r = 0; r < 4; ++r) {
        int rowi = i * 16 + crow0 + r;
        part[(zbase + rowi) * N + col] = acc[i][j][r];
      }
    }
  }
}

// ---------------- C[64][N] = sum_z part[z][64][N] + bias (opt. bf16 copy) ----------------
template <bool BF16OUT>
__global__ __launch_bounds__(256) void reduce_bias(const float* __restrict__ part,
                                                   const float* __restrict__ bias,
                                                   float* __restrict__ C,
                                                   __hip_bfloat16* __restrict__ Cb,
                                                   int N, int SK) {
  int i = blockIdx.x * 256 + threadIdx.x;  // < 64*N
  int col = i & (N - 1);                   // N is a power of two
  float s = bias[col];
  for (int z = 0; z < SK; ++z) s += part[(size_t)z * 64 * N + i];
  C[i] = s;
  if (BF16OUT) Cb[i] = __float2bfloat16(s);
}

// ---------------- combined cterm reduce: out[64][4096], bias = [rn_b1 | en_b1] ----------------
__global__ __launch_bounds__(256) void reduce_cterm(const float* __restrict__ part,
                                                    const float* __restrict__ rn_b1,
                                                    const float* __restrict__ en_b1,
                                                    float* __restrict__ out, int SK) {
  int i = blockIdx.x * 256 + threadIdx.x;  // < 64*4096
  int col = i & 4095;
  float s = (col < 2048) ? rn_b1[col] : en_b1[col - 2048];
  for (int z = 0; z < SK; ++z) s += part[(size_t)z * 64 * 4096 + i];
  out[i] = s;
}

// ---------------- fused split-K reduce + LayerNorm(2048) + relu -> bf16 (64 rows) ----------------
__global__ __launch_bounds__(256) void ln2048red(const float* __restrict__ part,
                                                 const float* __restrict__ bias,
                                                 const float* __restrict__ g,
                                                 const float* __restrict__ be,
                                                 __hip_bfloat16* __restrict__ out, int SK) {
  __shared__ float red[256];
  int row = blockIdx.x, t = threadIdx.x;
  int j0 = t * 8;
  float v[8];
  *(float4*)&v[0] = *(const float4*)(bias + j0);
  *(float4*)&v[4] = *(const float4*)(bias + j0 + 4);
  for (int z = 0; z < SK; ++z) {
    const float* p = part + (size_t)z * 64 * 2048 + (size_t)row * 2048 + j0;
    float4 a0 = *(const float4*)p, a1 = *(const float4*)(p + 4);
    v[0] += a0.x; v[1] += a0.y; v[2] += a0.z; v[3] += a0.w;
    v[4] += a1.x; v[5] += a1.y; v[6] += a1.z; v[7] += a1.w;
  }
  float s = 0.f;
#pragma unroll
  for (int j = 0; j < 8; ++j) s += v[j];
  red[t] = s; __syncthreads();
  for (int k = 128; k > 0; k >>= 1) { if (t < k) red[t] += red[t + k]; __syncthreads(); }
  float mean = red[0] * (1.0f / 2048.0f);
  __syncthreads();
  float s2 = 0.f;
#pragma unroll
  for (int j = 0; j < 8; ++j) { float d = v[j] - mean; s2 += d * d; }
  red[t] = s2; __syncthreads();
  for (int k = 128; k > 0; k >>= 1) { if (t < k) red[t] += red[t + k]; __syncthreads(); }
  float rstd = rsqrtf(red[0] * (1.0f / 2048.0f) + 1e-5f);
  __hip_bfloat16 o[8];
#pragma unroll
  for (int j = 0; j < 8; ++j) {
    float y = (v[j] - mean) * rstd * g[j0 + j] + be[j0 + j];
    o[j] = __float2bfloat16(fmaxf(y, 0.f));
  }
  *(vshort8*)&out[(size_t)row * 2048 + j0] = *(vshort8*)o;
}

// ---------------- combine (bf16 G) + LayerNorm + relu -> bf16 ----------------
template <int NEIGH>
__global__ __launch_bounds__(256) void ln_comb(const __hip_bfloat16* __restrict__ G,
                                               const float* __restrict__ cterm, int cstride,
                                               const float* __restrict__ g,
                                               const float* __restrict__ be,
                                               __hip_bfloat16* __restrict__ out) {
  __shared__ float red[256];
  int row = blockIdx.x, t = threadIdx.x;
  int j0 = t * 8;
  const int GS = NEIGH ? 4096 : 2048;
  float v[8];
  load_bf8(G + (size_t)row * GS + j0, v);
  {
    const float* p = cterm + (size_t)(row >> 5) * cstride + j0;
    float4 a0 = *(const float4*)p, a1 = *(const float4*)(p + 4);
    v[0] += a0.x; v[1] += a0.y; v[2] += a0.z; v[3] += a0.w;
    v[4] += a1.x; v[5] += a1.y; v[6] += a1.z; v[7] += a1.w;
  }
  if (NEIGH) {
    int f = row & 7;
    int prow = (f == 0) ? row : row - 1;
    int nrow = (f == NF_ - 1) ? row : row + 1;
    float a[8], b[8];
    load_bf8(G + (size_t)prow * 4096 + 2048 + j0, a);
    load_bf8(G + (size_t)nrow * 4096 + 2048 + j0, b);
#pragma unroll
    for (int j = 0; j < 8; ++j) v[j] += a[j] + b[j];
  }
  float s = 0.f;
#pragma unroll
  for (int j = 0; j < 8; ++j) s += v[j];
  red[t] = s; __syncthreads();
  for (int k = 128; k > 0; k >>= 1) { if (t < k) red[t] += red[t + k]; __syncthreads(); }
  float mean = red[0] * (1.0f / 2048.0f);
  __syncthreads();
  float s2 = 0.f;
#pragma unroll
  for (int j = 0; j < 8; ++j) { float d = v[j] - mean; s2 += d * d; }
  red[t] = s2; __syncthreads();
  for (int k = 128; k > 0; k >>= 1) { if (t < k) red[t] += red[t + k]; __syncthreads(); }
  float rstd = rsqrtf(red[0] * (1.0f / 2048.0f) + 1e-5f);
  __hip_bfloat16 o[8];
#pragma unroll
  for (int j = 0; j < 8; ++j) {
    float y = (v[j] - mean) * rstd * g[j0 + j] + be[j0 + j];
    o[j] = __float2bfloat16(fmaxf(y, 0.f));
  }
  *(vshort8*)&out[(size_t)row * 2048 + j0] = *(vshort8*)o;
}

// ---------------- bf16 MFMA GEMM via global_load_lds, BK=64, tile 128x64 ----------------
// MODE 4: raw bf16 out (used for the big N=4096 loop GEMM)
template <int MODE>
__global__ __launch_bounds__(256) void gemm_gl(const __hip_bfloat16* __restrict__ A,
                                               const __hip_bfloat16* __restrict__ Bt,
                                               const float* __restrict__ bias,
                                               float* __restrict__ Cout,
                                               __hip_bfloat16* __restrict__ Cbout,
                                               int M, int N, int K, int it) {
  __shared__ short Als[128 * 64];  // 16 KB linear
  __shared__ short Bls[64 * 64];   // 8 KB linear
  int t = threadIdx.x;
  int lane = t & 63, wv = t >> 6;
  int n0 = blockIdx.x * 64, m0 = blockIdx.y * 128;
  int wm = (wv >> 1) * 64, wn = (wv & 1) * 32;
  int lrow = lane & 15, kb = (lane >> 4) * 8;
  vfloat4 acc[4][2];
#pragma unroll
  for (int i = 0; i < 4; ++i)
#pragma unroll
    for (int j = 0; j < 2; ++j) acc[i][j] = (vfloat4){0.f, 0.f, 0.f, 0.f};
  const short* Ag = (const short*)A;
  const short* Bg = (const short*)Bt;
  int arow = lane >> 3;        // 0..7 (8 lanes per 128B row)
  int acol = (lane & 7) * 8;   // shorts
  for (int k0 = 0; k0 < K; k0 += 64) {
#pragma unroll
    for (int c = 0; c < 4; ++c)
      gload16(Ag + (size_t)(m0 + c * 32 + wv * 8 + arow) * K + k0 + acol,
              &Als[(c * 32 + wv * 8) * 64]);
#pragma unroll
    for (int c = 0; c < 2; ++c)
      gload16(Bg + (size_t)(n0 + c * 32 + wv * 8 + arow) * K + k0 + acol,
              &Bls[(c * 32 + wv * 8) * 64]);
    __syncthreads();
    vbf16x8 af[2][4], bq[2][2];
#pragma unroll
    for (int ks = 0; ks < 2; ++ks) {
#pragma unroll
      for (int i = 0; i < 4; ++i)
        af[ks][i] = *(const vbf16x8*)&Als[(wm + i * 16 + lrow) * 64 + ks * 32 + kb];
#pragma unroll
      for (int j = 0; j < 2; ++j)
        bq[ks][j] = *(const vbf16x8*)&Bls[(wn + j * 16 + lrow) * 64 + ks * 32 + kb];
    }
#pragma unroll
    for (int ks = 0; ks < 2; ++ks)
#pragma unroll
      for (int i = 0; i < 4; ++i)
#pragma unroll
        for (int j = 0; j < 2; ++j)
          acc[i][j] = __builtin_amdgcn_mfma_f32_16x16x32_bf16(af[ks][i], bq[ks][j], acc[i][j], 0, 0, 0);
    __syncthreads();
  }
  int crow0 = m0 + wm + (lane >> 4) * 4;
  int ccol0 = n0 + wn + lrow;
  if (MODE == 4) {
#pragma unroll
    for (int i = 0; i < 4; ++i) {
#pragma unroll
      for (int j = 0; j < 2; ++j) {
        int col = ccol0 + j * 16;
#pragma unroll
        for (int r = 0; r < 4; ++r)
          Cbout[(size_t)(crow0 + i * 16 + r) * N + col] = __float2bfloat16(acc[i][j][r]);
      }
    }
  } else {
#pragma unroll
    for (int i = 0; i < 4; ++i) {
#pragma unroll
      for (int j = 0; j < 2; ++j) {
        int col = ccol0 + j * 16;
        float bv = bias[col];
#pragma unroll
        for (int r = 0; r < 4; ++r) {
          float v = acc[i][j][r] + bv;
          if (MODE == 1) v = fmaxf(v, 0.f);
          Cout[(size_t)(crow0 + i * 16 + r) * N + col] = v;
        }
      }
    }
  }
}

// ---------------- bf16 MFMA GEMM, tile 128x32 (2 blocks/CU for N=1024 GEMMs) ----------------
// MODE 1: bias+relu (f32 out); MODE 2: fused x-update + bf16 x copy
template <int MODE>
__global__ __launch_bounds__(256) void gemm_gl32(const __hip_bfloat16* __restrict__ A,
                                                 const __hip_bfloat16* __restrict__ Bt,
                                                 const float* __restrict__ bias,
                                                 float* __restrict__ Cout,
                                                 __hip_bfloat16* __restrict__ Cbout,
                                                 int M, int N, int K, int it) {
  __shared__ short Als[128 * 64];  // 16 KB linear
  __shared__ short Bls[32 * 64];   // 4 KB linear
  int t = threadIdx.x;
  int lane = t & 63, wv = t >> 6;
  int n0 = blockIdx.x * 32, m0 = blockIdx.y * 128;
  int wm = wv * 32;
  int lrow = lane & 15, kb = (lane >> 4) * 8;
  vfloat4 acc[2][2];
#pragma unroll
  for (int i = 0; i < 2; ++i)
#pragma unroll
    for (int j = 0; j < 2; ++j) acc[i][j] = (vfloat4){0.f, 0.f, 0.f, 0.f};
  const short* Ag = (const short*)A;
  const short* Bg = (const short*)Bt;
  int arow = lane >> 3;        // 0..7 (8 lanes per 128B row)
  int acol = (lane & 7) * 8;   // shorts
  for (int k0 = 0; k0 < K; k0 += 64) {
#pragma unroll
    for (int c = 0; c < 4; ++c)
      gload16(Ag + (size_t)(m0 + c * 32 + wv * 8 + arow) * K + k0 + acol,
              &Als[(c * 32 + wv * 8) * 64]);
    gload16(Bg + (size_t)(n0 + wv * 8 + arow) * K + k0 + acol, &Bls[(wv * 8) * 64]);
    __syncthreads();
    vbf16x8 af[2][2], bq[2][2];
#pragma unroll
    for (int ks = 0; ks < 2; ++ks) {
#pragma unroll
      for (int i = 0; i < 2; ++i)
        af[ks][i] = *(const vbf16x8*)&Als[(wm + i * 16 + lrow) * 64 + ks * 32 + kb];
#pragma unroll
      for (int j = 0; j < 2; ++j)
        bq[ks][j] = *(const vbf16x8*)&Bls[(j * 16 + lrow) * 64 + ks * 32 + kb];
    }
#pragma unroll
    for (int ks = 0; ks < 2; ++ks)
#pragma unroll
      for (int i = 0; i < 2; ++i)
#pragma unroll
        for (int j = 0; j < 2; ++j)
          acc[i][j] = __builtin_amdgcn_mfma_f32_16x16x32_bf16(af[ks][i], bq[ks][j], acc[i][j], 0, 0, 0);
    __syncthreads();
  }
  int crow0 = m0 + wm + (lane >> 4) * 4;
  int ccol0 = n0 + lrow;
  if (MODE == 2) {
    uint32_t key0 = 0, key1 = 0;
    bool addn = (it < NIT_ - 1);
    if (addn) threefry2x32(0u, 7u, 0u, (uint32_t)it, key0, key1);  // fold_in(key(7), it)
#pragma unroll
    for (int i = 0; i < 2; ++i) {
#pragma unroll
      for (int j = 0; j < 2; ++j) {
        int col = ccol0 + j * 16;
        float bv = bias[col];
#pragma unroll
        for (int r = 0; r < 4; ++r) {
          uint32_t idx = (uint32_t)(crow0 + i * 16 + r) * N + col;
          float xv = Cout[idx] - 0.1f * (acc[i][j][r] + bv);
          if (addn) xv += 0.01f * bits_to_normal(tf_bits_part(key0, key1, idx));
          Cout[idx] = xv;
          Cbout[idx] = __float2bfloat16(xv);
        }
      }
    }
  } else {
#pragma unroll
    for (int i = 0; i < 2; ++i) {
#pragma unroll
      for (int j = 0; j < 2; ++j) {
        int col = ccol0 + j * 16;
        float bv = bias[col];
#pragma unroll
        for (int r = 0; r < 4; ++r) {
          float v = acc[i][j][r] + bv;
          if (MODE == 1) v = fmaxf(v, 0.f);
          Cout[(size_t)(crow0 + i * 16 + r) * N + col] = v;
        }
      }
    }
  }
}

// ---------------- fused: traj = reduce(part)+bias; x[b,h] = traj + 0.1*normal ----------------
__global__ __launch_bounds__(256) void reduce_traj_noise(const float* __restrict__ part,
                                                         const float* __restrict__ bias,
                                                         float* __restrict__ x,
                                                         __hip_bfloat16* __restrict__ xb,
                                                         int SK) {
  int i = blockIdx.x * 256 + threadIdx.x;  // < 524288 (traj index)
  int fe = i & 8191;
  float s = bias[fe];
  for (int z = 0; z < SK; ++z) s += part[(size_t)z * 524288 + i];
  int b = i >> 13;
#pragma unroll
  for (int h = 0; h < NH_; ++h) {
    uint32_t xi = (uint32_t)(b * 32768 + h * 8192 + fe);
    float xv = s + 0.1f * bits_to_normal(tf_bits_part(0u, 42u, xi));
    x[xi] = xv;
    xb[xi] = __float2bfloat16(xv);
  }
}

// ---------------- fused coherence + smoothness + supervision per bh ----------------
__global__ __launch_bounds__(256) void energy_final2(const float* __restrict__ u,
                                                     const float* __restrict__ w3,
                                                     const float* __restrict__ b3,
                                                     const float* __restrict__ x,
                                                     const float* __restrict__ ft,
                                                     float* __restrict__ energ) {
  __shared__ float red[256];
  int bh = blockIdx.x, t = threadIdx.x;
  int b = bh >> 2;
  const float* ur = u + (size_t)bh * (NF_ * 1024);
  const float* xb = x + (size_t)bh * (NF_ * E_);
  const float* fb = ft + (size_t)b * (NF_ * E_);
  // coherence = mean_f(dot(u_row, w3)) + b3
  float c = 0.f;
  for (int i = t; i < NF_ * 1024; i += 256) c += ur[i] * w3[i & 1023];
  red[t] = c; __syncthreads();
  for (int k = 128; k > 0; k >>= 1) { if (t < k) red[t] += red[t + k]; __syncthreads(); }
  float coh = red[0] * (1.0f / NF_) + b3[0];
  __syncthreads();
  // supervision
  float sup = 0.f;
  for (int i = t; i < NF_ * E_; i += 256) { float d = xb[i] - fb[i]; sup += d * d; }
  red[t] = sup; __syncthreads();
  for (int k = 128; k > 0; k >>= 1) { if (t < k) red[t] += red[t + k]; __syncthreads(); }
  float supervision = red[0] / (NF_ * E_);
  float smooth = 0.f;
  for (int d = 0; d < NF_ - 1; ++d) {
    __syncthreads();
    float sd = 0.f;
    for (int e = t; e < E_; e += 256) {
      float df = xb[(d + 1) * E_ + e] - xb[d * E_ + e];
      sd += df * df;
    }
    red[t] = sd; __syncthreads();
    for (int k = 128; k > 0; k >>= 1) { if (t < k) red[t] += red[t + k]; __syncthreads(); }
    smooth += sqrtf(red[0]);
  }
  smooth *= (1.0f / (NF_ - 1));
  if (t == 0) energ[bh] = coh + 0.1f * smooth + supervision;
}

// ---------------- softmax (inline) + weighted prediction ----------------
__global__ __launch_bounds__(256) void predict2(const float* __restrict__ x,
                                                const float* __restrict__ energ,
                                                float* __restrict__ out) {
  __shared__ float pr[NH_];
  int i = blockIdx.x * 256 + threadIdx.x;  // < 524288
  int b = i >> 13, fe = i & 8191;
  if (threadIdx.x == 0) {
    float e[NH_], m = -1e30f;
#pragma unroll
    for (int h = 0; h < NH_; ++h) { e[h] = -energ[b * NH_ + h]; m = fmaxf(m, e[h]); }
    float s = 0.f, p[NH_];
#pragma unroll
    for (int h = 0; h < NH_; ++h) { p[h] = expf(e[h] - m); s += p[h]; }
#pragma unroll
    for (int h = 0; h < NH_; ++h) pr[h] = p[h] / s;
  }
  __syncthreads();
  float s = 0.f;
#pragma unroll
  for (int h = 0; h < NH_; ++h) s += x[(size_t)(b * NH_ + h) * 8192 + fe] * pr[h];
  out[i] = s;
}

extern "C" void kernel_launch(void* const* d_in, const int* in_sizes, int n_in,
                              void* d_out, int out_size, void* d_ws, size_t ws_size,
                              hipStream_t stream) {
  const float* cur   = (const float*)d_in[0];
  const float* ftrue = (const float*)d_in[1];
  const float* ce_w1 = (const float*)d_in[2];
  const float* ce_b1 = (const float*)d_in[3];
  const float* ce_g  = (const float*)d_in[4];
  const float* ce_be = (const float*)d_in[5];
  const float* ce_w2 = (const float*)d_in[6];
  const float* ce_b2 = (const float*)d_in[7];
  const float* tp_w1 = (const float*)d_in[8];
  const float* tp_b1 = (const float*)d_in[9];
  const float* tp_g  = (const float*)d_in[10];
  const float* tp_be = (const float*)d_in[11];
  const float* tp_w2 = (const float*)d_in[12];
  const float* tp_b2 = (const float*)d_in[13];
  const float* en_w1 = (const float*)d_in[14];
  const float* en_b1 = (const float*)d_in[15];
  const float* en_g  = (const float*)d_in[16];
  const float* en_be = (const float*)d_in[17];
  const float* en_w2 = (const float*)d_in[18];
  const float* en_b2 = (const float*)d_in[19];
  const float* en_w3 = (const float*)d_in[20];
  const float* en_b3 = (const float*)d_in[21];
  const float* rn_w1 = (const float*)d_in[22];
  const float* rn_b1 = (const float*)d_in[23];
  const float* rn_g  = (const float*)d_in[24];
  const float* rn_be = (const float*)d_in[25];
  const float* rn_w2 = (const float*)d_in[26];
  const float* rn_b2 = (const float*)d_in[27];
  (void)in_sizes; (void)n_in; (void)out_size; (void)ws_size;

  char* w = (char*)d_ws;
  size_t off = 0;
  auto alloc = [&](size_t bytes) -> void* {
    void* p = w + off;
    off += (bytes + 255) & ~(size_t)255;
    return p;
  };
  float* part   = (float*)alloc((size_t)8 * B_ * E_ * 4);
  float* g1     = (float*)alloc((size_t)B_ * H_ * 4);
  float* x      = (float*)alloc((size_t)2097152 * 4);
  float* skpart = (float*)alloc((size_t)8 * 64 * 8192 * 4);  // 16.78 MB split-K partials
  __hip_bfloat16* Gb = (__hip_bfloat16*)alloc((size_t)2048 * 4096 * 2);  // big-GEMM output (bf16)
  float* u      = (float*)alloc((size_t)2048 * 1024 * 4);
  __hip_bfloat16* ub   = (__hip_bfloat16*)alloc((size_t)2048 * 2048 * 2);
  __hip_bfloat16* x_b  = (__hip_bfloat16*)alloc((size_t)2048 * 1024 * 2);
  float* energ  = (float*)alloc((size_t)256 * 4);
  float* ctermcat = (float*)alloc((size_t)B_ * 4096 * 4);  // [cterm | ecterm]
  __hip_bfloat16* Wcat_t  = (__hip_bfloat16*)alloc((size_t)4096 * 1024 * 2);  // [W1a; 0.5*W1c]^T
  __hip_bfloat16* Wbcat_t = (__hip_bfloat16*)alloc((size_t)4096 * 1024 * 2);  // [W1b; en_w1b]^T
  __hip_bfloat16* rn_w2t = (__hip_bfloat16*)alloc((size_t)1024 * 2048 * 2);
  __hip_bfloat16* en1a_t = (__hip_bfloat16*)alloc((size_t)2048 * 1024 * 2);
  __hip_bfloat16* en_w2t = (__hip_bfloat16*)alloc((size_t)1024 * 2048 * 2);
  __hip_bfloat16* ctx_b  = (__hip_bfloat16*)alloc((size_t)B_ * E_ * 2);
  __hip_bfloat16* ctxh_b = (__hip_bfloat16*)alloc((size_t)B_ * H_ * 2);
  __hip_bfloat16* lnb    = (__hip_bfloat16*)alloc((size_t)B_ * H_ * 2);
  __hip_bfloat16* cw1t = (__hip_bfloat16*)alloc((size_t)2048 * 1024 * 2);
  __hip_bfloat16* cw2t = (__hip_bfloat16*)alloc((size_t)2048 * 2048 * 2);
  __hip_bfloat16* tw1t = (__hip_bfloat16*)alloc((size_t)2048 * 2048 * 2);
  __hip_bfloat16* tw2t = (__hip_bfloat16*)alloc((size_t)8192 * 2048 * 2);

  // ctx = mean_S  (bf16 output directly)
  colmean_partial<<<512, 256, 0, stream>>>(cur, part);
  colmean_final_bf<<<256, 256, 0, stream>>>(part, ctx_b);

  // weight prep: ONE batched transpose launch (11 descriptors, 40960 tiles)
  TDArr ta;
  int base = 0;
  auto set = [&](int idx, const float* src, __hip_bfloat16* dst, int K, int N, float sc) {
    ta.d[idx] = TD{src, dst, K, N, sc, base};
    base += (N >> 5) * (K >> 5);
  };
  set(0, rn_w1, Wcat_t, 1024, 2048, 1.0f);
  set(1, rn_w1 + (size_t)2048 * 2048, Wcat_t + (size_t)2048 * 1024, 1024, 2048, 0.5f);
  set(2, rn_w1 + (size_t)1024 * 2048, Wbcat_t, 1024, 2048, 1.0f);
  set(3, en_w1 + (size_t)1024 * 2048, Wbcat_t + (size_t)2048 * 1024, 1024, 2048, 1.0f);
  set(4, rn_w2, rn_w2t, 2048, 1024, 1.0f);
  set(5, en_w1, en1a_t, 1024, 2048, 1.0f);
  set(6, en_w2, en_w2t, 2048, 1024, 1.0f);
  set(7, ce_w1, cw1t, 1024, 2048, 1.0f);
  set(8, ce_w2, cw2t, 2048, 2048, 1.0f);
  set(9, tp_w1, tw1t, 2048, 2048, 1.0f);
  set(10, tp_w2, tw2t, 2048, 8192, 1.0f);
  transpose_batch<<<base, 256, 0, stream>>>(ta);

  // ---- context/trajectory path (plain bf16 skinny GEMMs, M=64) ----
  mfma_skinny<<<dim3(16, 4), 256, 0, stream>>>(ctx_b, cw1t, skpart, 2048, 1024, 1024, 256);
  ln2048red<<<B_, 256, 0, stream>>>(skpart, ce_b1, ce_g, ce_be, lnb, 4);
  mfma_skinny<<<dim3(16, 8), 256, 0, stream>>>(lnb, cw2t, skpart, 2048, 2048, 2048, 256);
  reduce_bias<true><<<512, 256, 0, stream>>>(skpart, ce_b2, g1, ctxh_b, 2048, 8);
  mfma_skinny<<<dim3(16, 8), 256, 0, stream>>>(ctxh_b, tw1t, skpart, 2048, 2048, 2048, 256);
  ln2048red<<<B_, 256, 0, stream>>>(skpart, tp_b1, tp_g, tp_be, lnb, 8);
  mfma_skinny<<<dim3(64, 8), 256, 0, stream>>>(lnb, tw2t, skpart, 8192, 2048, 2048, 256);
  reduce_traj_noise<<<2048, 256, 0, stream>>>(skpart, tp_b2, x, x_b, 8);

  // constant terms (once): [cterm | ecterm] = ce @ [W1b | en_w1b] + [rn_b1 | en_b1]
  mfma_skinny<<<dim3(32, 4), 256, 0, stream>>>(ctxh_b, Wbcat_t, skpart, 4096, 1024, 2048, 256);
  reduce_cterm<<<1024, 256, 0, stream>>>(skpart, rn_b1, en_b1, ctermcat, 4);

  // refinement loop: 3 dispatches/iter
  for (int it = 0; it < NIT_; ++it) {
    gemm_gl<4><<<dim3(64, 16), 256, 0, stream>>>(x_b, Wcat_t, nullptr, nullptr, Gb,
                                                 2048, 4096, 1024, 0);
    ln_comb<1><<<2048, 256, 0, stream>>>(Gb, ctermcat, 4096, rn_g, rn_be, ub);
    gemm_gl32<2><<<dim3(32, 16), 256, 0, stream>>>(ub, rn_w2t, rn_b2, x, x_b,
                                                   2048, 1024, 2048, it);
  }

  // energy + softmax + weighted prediction
  gemm_gl<4><<<dim3(32, 16), 256, 0, stream>>>(x_b, en1a_t, nullptr, nullptr, Gb,
                                               2048, 2048, 1024, 0);
  ln_comb<0><<<2048, 256, 0, stream>>>(Gb, ctermcat + 2048, 4096, en_g, en_be, ub);
  gemm_gl32<1><<<dim3(32, 16), 256, 0, stream>>>(ub, en_w2t, en_b2, u, nullptr,
                                                 2048, 1024, 2048, 0);
  energy_final2<<<256, 256, 0, stream>>>(u, en_w3, en_b3, x, ftrue, energ);
  predict2<<<2048, 256, 0, stream>>>(x, energ, (float*)d_out);
}